// Round 2
// baseline (2206.271 us; speedup 1.0000x reference)
//
#include <hip/hip_runtime.h>
#include <hip/hip_bf16.h>
#include <math.h>

// Problem constants (from reference)
//   N=50000 nodes, E=640000 edges, M=400000 samples
//   D_IN=256, H1=128, H2=128, H3=64, D_OUT=32
//
// Round 1: resubmit of round-0 baseline (round-0 bench died at container
// acquisition, not in the kernel). No functional changes.

// ---------------------------------------------------------------------------
// degree / norm kernels
// ---------------------------------------------------------------------------
__global__ void init_deg_kernel(float* __restrict__ deg, int n) {
    int i = blockIdx.x * 256 + threadIdx.x;
    if (i < n) deg[i] = 1.0f;  // self-loop contributes 1
}

__global__ void deg_accum_kernel(float* __restrict__ deg, const int* __restrict__ dst, int e) {
    int i = blockIdx.x * 256 + threadIdx.x;
    if (i < e) atomicAdd(&deg[dst[i]], 1.0f);
}

__global__ void rsqrt_kernel(float* __restrict__ deg, int n) {
    int i = blockIdx.x * 256 + threadIdx.x;
    if (i < n) deg[i] = rsqrtf(deg[i]);  // deg -> dis in place
}

// ---------------------------------------------------------------------------
// Generic fp32 vector GEMM:  Y[r, col0:col0+NT] = act( X[r,:]@W + bias )
//   Block: 256 threads, tile 64 rows x NT cols, K-tiled by 64.
//   Each thread: RT rows x 4 cols micro-tile.
//   ACT: 0=none, 1=leaky_relu(0.01).  ELU_IN: apply elu() to X on load.
// ---------------------------------------------------------------------------
template <int K, int NC, int NT, int ACT, bool ELU_IN, bool BIAS>
__global__ __launch_bounds__(256) void gemm_kernel(
    const float* __restrict__ X, const float* __restrict__ W,
    const float* __restrict__ bias, float* __restrict__ Y, int nrows)
{
    constexpr int KT = 64;
    constexpr int CG = NT / 4;    // col groups (threads across cols)
    constexpr int RG = 256 / CG;  // row groups
    constexpr int RT = 64 / RG;   // rows per thread

    __shared__ float xs[64 * (KT + 1)];  // +1 pad: kill stride-64 bank conflicts
    __shared__ float ws[KT * NT];

    const int t   = threadIdx.x;
    const int tx  = t % CG;
    const int ty  = t / CG;
    const int row0 = blockIdx.y * 64;
    const int col0 = blockIdx.x * NT;

    float acc[RT][4];
#pragma unroll
    for (int i = 0; i < RT; ++i) {
        acc[i][0] = 0.f; acc[i][1] = 0.f; acc[i][2] = 0.f; acc[i][3] = 0.f;
    }

    for (int kt = 0; kt < K; kt += KT) {
        // stage X tile (64 rows x KT) with optional elu
#pragma unroll
        for (int i = 0; i < (64 * KT) / 256; ++i) {
            int f = t + 256 * i;
            int r = f >> 6;          // KT == 64
            int c = f & 63;
            int gr = row0 + r;
            float v = 0.f;
            if (gr < nrows) v = X[(size_t)gr * K + kt + c];
            if (ELU_IN) v = (v > 0.f) ? v : expm1f(v);
            xs[r * (KT + 1) + c] = v;
        }
        // stage W tile (KT x NT)
#pragma unroll
        for (int i = 0; i < (KT * NT) / 256; ++i) {
            int f = t + 256 * i;
            int r = f / NT;
            int c = f % NT;
            ws[r * NT + c] = W[(size_t)(kt + r) * NC + col0 + c];
        }
        __syncthreads();

#pragma unroll
        for (int k = 0; k < KT; ++k) {
            float4 wv = *(const float4*)&ws[k * NT + tx * 4];
#pragma unroll
            for (int i = 0; i < RT; ++i) {
                float xv = xs[(ty * RT + i) * (KT + 1) + k];
                acc[i][0] += xv * wv.x;
                acc[i][1] += xv * wv.y;
                acc[i][2] += xv * wv.z;
                acc[i][3] += xv * wv.w;
            }
        }
        __syncthreads();
    }

    float4 bv = make_float4(0.f, 0.f, 0.f, 0.f);
    if (BIAS) bv = *(const float4*)&bias[col0 + tx * 4];

#pragma unroll
    for (int i = 0; i < RT; ++i) {
        int gr = row0 + ty * RT + i;
        if (gr < nrows) {
            float4 o;
            o.x = acc[i][0] + bv.x;
            o.y = acc[i][1] + bv.y;
            o.z = acc[i][2] + bv.z;
            o.w = acc[i][3] + bv.w;
            if (ACT == 1) {
                o.x = (o.x > 0.f) ? o.x : 0.01f * o.x;
                o.y = (o.y > 0.f) ? o.y : 0.01f * o.y;
                o.z = (o.z > 0.f) ? o.z : 0.01f * o.z;
                o.w = (o.w > 0.f) ? o.w : 0.01f * o.w;
            }
            *(float4*)&Y[(size_t)gr * NC + col0 + tx * 4] = o;
        }
    }
}

// ---------------------------------------------------------------------------
// agg[i,:] = h[i,:] * dis[i]^2    (self-loop init; n4 = N*32 float4s)
// ---------------------------------------------------------------------------
__global__ void selfloop_kernel(const float* __restrict__ h, const float* __restrict__ dis,
                                float* __restrict__ agg, int n4) {
    int i = blockIdx.x * 256 + threadIdx.x;
    if (i >= n4) return;
    int row = i >> 5;  // 32 float4 per row of 128
    float d = dis[row];
    float s = d * d;
    float4 v = ((const float4*)h)[i];
    v.x *= s; v.y *= s; v.z *= s; v.w *= s;
    ((float4*)agg)[i] = v;
}

// ---------------------------------------------------------------------------
// Edge scatter: agg[dst,:] += h[src,:] * dis[src]*dis[dst]
//   one wave (64 lanes) per edge, float2 per lane (128 floats / row)
// ---------------------------------------------------------------------------
__global__ void scatter_kernel(const float* __restrict__ h, const int* __restrict__ src,
                               const int* __restrict__ dst, const float* __restrict__ dis,
                               float* __restrict__ agg, int e) {
    int eid  = blockIdx.x * 4 + (threadIdx.x >> 6);
    int lane = threadIdx.x & 63;
    if (eid >= e) return;
    int s = src[eid];
    int d = dst[eid];
    float nrm = dis[s] * dis[d];
    float2 v = ((const float2*)(h + (size_t)s * 128))[lane];
    atomicAdd(&agg[(size_t)d * 128 + lane * 2 + 0], v.x * nrm);
    atomicAdd(&agg[(size_t)d * 128 + lane * 2 + 1], v.y * nrm);
}

// ---------------------------------------------------------------------------
// decoder: out[s] = dot32(tf[ts[s,0]], tg[ts[s,1]])   (8 lanes per sample)
// ---------------------------------------------------------------------------
__global__ void dot_kernel(const float* __restrict__ tf, const float* __restrict__ tg,
                           const int* __restrict__ ts, float* __restrict__ out, int m) {
    int gid = blockIdx.x * 256 + threadIdx.x;
    int s = gid >> 3;
    int l = gid & 7;
    if (s >= m) return;
    int ti = ts[2 * s + 0];
    int ui = ts[2 * s + 1];
    float4 a = ((const float4*)(tf + (size_t)ti * 32))[l];
    float4 b = ((const float4*)(tg + (size_t)ui * 32))[l];
    float d = a.x * b.x + a.y * b.y + a.z * b.z + a.w * b.w;
    d += __shfl_down(d, 4, 8);
    d += __shfl_down(d, 2, 8);
    d += __shfl_down(d, 1, 8);
    if (l == 0) out[s] = d;
}

// ---------------------------------------------------------------------------
extern "C" void kernel_launch(void* const* d_in, const int* in_sizes, int n_in,
                              void* d_out, int out_size, void* d_ws, size_t ws_size,
                              hipStream_t stream) {
    const float* x     = (const float*)d_in[0];
    const int*   ei    = (const int*)d_in[1];
    const int*   ts    = (const int*)d_in[2];
    const float* W1    = (const float*)d_in[3];
    const float* W2    = (const float*)d_in[4];
    const float* tf_w1 = (const float*)d_in[5];
    const float* tf_b1 = (const float*)d_in[6];
    const float* tf_w2 = (const float*)d_in[7];
    const float* tf_b2 = (const float*)d_in[8];
    const float* tg_w1 = (const float*)d_in[9];
    const float* tg_b1 = (const float*)d_in[10];
    const float* tg_w2 = (const float*)d_in[11];
    const float* tg_b2 = (const float*)d_in[12];
    float* out = (float*)d_out;

    const int n = in_sizes[0] / 256;   // 50000
    const int e = in_sizes[1] / 2;     // 640000
    const int m = in_sizes[2] / 2;     // 400000
    const int* src = ei;
    const int* dstp = ei + e;

    // workspace layout (floats): dis[N] | A[N*128] | B[N*128] | C[N*128]
    float* wsf = (float*)d_ws;
    float* dis = wsf;
    float* A = wsf + 50048;               // 16B-aligned
    float* B = A + (size_t)n * 128;
    float* C = B + (size_t)n * 128;

    const int nb_n = (n + 255) / 256;
    const int nb_e = (e + 255) / 256;
    const int gy   = (n + 63) / 64;

    // 1) normalization coefficients
    init_deg_kernel<<<nb_n, 256, 0, stream>>>(dis, n);
    deg_accum_kernel<<<nb_e, 256, 0, stream>>>(dis, dstp, e);
    rsqrt_kernel<<<nb_n, 256, 0, stream>>>(dis, n);

    // 2) layer 1: A = x@W1 ; B = scatter(A) ; (elu deferred into gemm2 load)
    gemm_kernel<256, 128, 64, 0, false, false><<<dim3(2, gy), 256, 0, stream>>>(x, W1, nullptr, A, n);
    selfloop_kernel<<<(n * 32 + 255) / 256, 256, 0, stream>>>(A, dis, B, n * 32);
    scatter_kernel<<<(e + 3) / 4, 256, 0, stream>>>(A, src, dstp, dis, B, e);

    // 3) layer 2: C = elu(B)@W2 ; A = scatter(C)  (A = embed)
    gemm_kernel<128, 128, 64, 0, true, false><<<dim3(2, gy), 256, 0, stream>>>(B, W2, nullptr, C, n);
    selfloop_kernel<<<(n * 32 + 255) / 256, 256, 0, stream>>>(C, dis, A, n * 32);
    scatter_kernel<<<(e + 3) / 4, 256, 0, stream>>>(C, src, dstp, dis, A, e);

    // 4) heads: tf1 -> B[0:N*64), tg1 -> B[N*64:), tf2 -> C[0:N*32), tg2 -> C[N*32:)
    float* tf1 = B;
    float* tg1 = B + (size_t)n * 64;
    float* tf2 = C;
    float* tg2 = C + (size_t)n * 32;
    gemm_kernel<128, 64, 64, 1, false, true><<<dim3(1, gy), 256, 0, stream>>>(A, tf_w1, tf_b1, tf1, n);
    gemm_kernel< 64, 32, 32, 1, false, true><<<dim3(1, gy), 256, 0, stream>>>(tf1, tf_w2, tf_b2, tf2, n);
    gemm_kernel<128, 64, 64, 1, false, true><<<dim3(1, gy), 256, 0, stream>>>(A, tg_w1, tg_b1, tg1, n);
    gemm_kernel< 64, 32, 32, 1, false, true><<<dim3(1, gy), 256, 0, stream>>>(tg1, tg_w2, tg_b2, tg2, n);

    // 5) decoder
    dot_kernel<<<(m * 8 + 255) / 256, 256, 0, stream>>>(tf2, tg2, ts, out, m);
}

// Round 4
// 1919.520 us; speedup vs baseline: 1.1494x; 1.1494x over previous
//
#include <hip/hip_runtime.h>
#include <hip/hip_bf16.h>
#include <math.h>

// Problem constants: N=50000, E=640000, M=400000
// D_IN=256, H1=128, H2=128, H3=64, D_OUT=32
//
// Round 3: identical resubmit of round-2 (GPU acquisition timeout, no data).
// Round 2: replace atomic edge-scatter (164M float atomics, ~1.55ms) with
// CSR build + per-node gather. Cap GEMM VGPRs via launch_bounds(256,4),
// vectorize LDS staging.

// ---------------------------------------------------------------------------
__global__ void zero_ideg_kernel(int* __restrict__ ideg, int n) {
    int i = blockIdx.x * 256 + threadIdx.x;
    if (i < n) ideg[i] = 0;
}

__global__ void ideg_accum_kernel(int* __restrict__ ideg, const int* __restrict__ dst, int e) {
    int i = blockIdx.x * 256 + threadIdx.x;
    if (i < e) atomicAdd(&ideg[dst[i]], 1);
}

// Single-block exclusive scan of ideg -> row_ptr, plus dis = rsqrt(1+deg).
// 1024 threads, wave-level shfl scan + cross-wave LDS combine.
__global__ __launch_bounds__(1024) void scan_kernel(const int* __restrict__ ideg,
                                                    int* __restrict__ row_ptr,
                                                    float* __restrict__ dis, int n) {
    __shared__ int wsum[16];
    __shared__ int chunk_carry;
    const int tid = threadIdx.x;
    const int lane = tid & 63;
    const int wid = tid >> 6;
    if (tid == 0) chunk_carry = 0;
    __syncthreads();
    for (int base = 0; base < n; base += 1024) {
        int i = base + tid;
        int v = (i < n) ? ideg[i] : 0;
        if (i < n) dis[i] = rsqrtf(1.0f + (float)v);  // self-loop adds 1
        // inclusive scan within wave
        int incl = v;
#pragma unroll
        for (int off = 1; off < 64; off <<= 1) {
            int t = __shfl_up(incl, off, 64);
            if (lane >= off) incl += t;
        }
        if (lane == 63) wsum[wid] = incl;
        __syncthreads();
        if (wid == 0 && lane < 16) {
            int s = wsum[lane];
            int sc = s;
#pragma unroll
            for (int off = 1; off < 16; off <<= 1) {
                int t = __shfl_up(sc, off, 64);
                if (lane >= off) sc += t;
            }
            wsum[lane] = sc - s;  // exclusive wave offset
        }
        __syncthreads();
        int excl = chunk_carry + wsum[wid] + (incl - v);
        if (i < n) row_ptr[i] = excl;
        __syncthreads();  // everyone done reading chunk_carry/wsum
        if (tid == 1023) chunk_carry = excl + v;
        __syncthreads();
    }
    if (tid == 0) row_ptr[n] = chunk_carry;  // = e (unused, for sanity)
}

// Bucket fill. atomicAdd(&row_ptr[d],1) returns the absolute slot; afterwards
// row_ptr[d] == original row_ptr[d+1], so gather uses beg=row_ptr[d-1], end=row_ptr[d].
__global__ void fill_kernel(const int* __restrict__ src, const int* __restrict__ dst,
                            int* __restrict__ row_ptr, int* __restrict__ csr, int e) {
    int i = blockIdx.x * 256 + threadIdx.x;
    if (i < e) {
        int d = dst[i];
        int pos = atomicAdd(&row_ptr[d], 1);
        csr[pos] = src[i];
    }
}

// ---------------------------------------------------------------------------
// Gather aggregation: out[d,:] = dis[d] * ( h[d]*dis[d] + sum_{s in N(d)} h[s]*dis[s] )
// One wave per node, float2 per lane (128 floats/row). No atomics.
// ---------------------------------------------------------------------------
__global__ __launch_bounds__(256) void gather_kernel(const float* __restrict__ h,
                                                     const int* __restrict__ row_ptr,
                                                     const int* __restrict__ csr,
                                                     const float* __restrict__ dis,
                                                     float* __restrict__ outp, int n) {
    int node = blockIdx.x * 4 + (threadIdx.x >> 6);
    int lane = threadIdx.x & 63;
    if (node >= n) return;
    int beg = (node == 0) ? 0 : row_ptr[node - 1];
    int end = row_ptr[node];
    float dd = dis[node];
    const float2* h2 = (const float2*)h;
    float2 self = h2[(size_t)node * 64 + lane];
    float ax = self.x * dd;
    float ay = self.y * dd;
    int j = beg;
    for (; j + 4 <= end; j += 4) {
        int s0 = csr[j + 0], s1 = csr[j + 1], s2 = csr[j + 2], s3 = csr[j + 3];
        float d0 = dis[s0], d1 = dis[s1], d2 = dis[s2], d3 = dis[s3];
        float2 v0 = h2[(size_t)s0 * 64 + lane];
        float2 v1 = h2[(size_t)s1 * 64 + lane];
        float2 v2 = h2[(size_t)s2 * 64 + lane];
        float2 v3 = h2[(size_t)s3 * 64 + lane];
        ax += v0.x * d0 + v1.x * d1 + v2.x * d2 + v3.x * d3;
        ay += v0.y * d0 + v1.y * d1 + v2.y * d2 + v3.y * d3;
    }
    for (; j < end; ++j) {
        int s = csr[j];
        float ds = dis[s];
        float2 v = h2[(size_t)s * 64 + lane];
        ax += v.x * ds;
        ay += v.y * ds;
    }
    float2 o;
    o.x = ax * dd;
    o.y = ay * dd;
    ((float2*)outp)[(size_t)node * 64 + lane] = o;
}

// ---------------------------------------------------------------------------
// fp32 vector GEMM: Y[r, col0:col0+NT] = act( X[r,:]@W + bias )
// 256 threads, 64-row x NT-col tile, K-tiled by 64, float4 staging.
// ---------------------------------------------------------------------------
template <int K, int NC, int NT, int ACT, bool ELU_IN, bool BIAS>
__global__ __launch_bounds__(256, 4) void gemm_kernel(
    const float* __restrict__ X, const float* __restrict__ W,
    const float* __restrict__ bias, float* __restrict__ Y, int nrows)
{
    constexpr int KT = 64;
    constexpr int XS_LD = KT + 4;  // 68: float4-aligned rows, <=2-way bank alias (free)
    constexpr int CG = NT / 4;     // threads across cols
    constexpr int RG = 256 / CG;   // row groups
    constexpr int RT = 64 / RG;    // rows per thread

    __shared__ float xs[64 * XS_LD];
    __shared__ float ws[KT * NT];

    const int t = threadIdx.x;
    const int tx = t % CG;
    const int ty = t / CG;
    const int row0 = blockIdx.y * 64;
    const int col0 = blockIdx.x * NT;

    float acc[RT][4];
#pragma unroll
    for (int i = 0; i < RT; ++i) {
        acc[i][0] = 0.f; acc[i][1] = 0.f; acc[i][2] = 0.f; acc[i][3] = 0.f;
    }

    for (int kt = 0; kt < K; kt += KT) {
        // stage X tile: 64 rows x 64 cols = 1024 float4, 4 per thread
#pragma unroll
        for (int i = 0; i < 4; ++i) {
            int f = t + 256 * i;
            int r = f >> 4;      // 16 float4 per row
            int c4 = f & 15;
            int gr = row0 + r;
            float4 v = make_float4(0.f, 0.f, 0.f, 0.f);
            if (gr < nrows) v = *(const float4*)&X[(size_t)gr * K + kt + c4 * 4];
            if (ELU_IN) {
                v.x = (v.x > 0.f) ? v.x : expm1f(v.x);
                v.y = (v.y > 0.f) ? v.y : expm1f(v.y);
                v.z = (v.z > 0.f) ? v.z : expm1f(v.z);
                v.w = (v.w > 0.f) ? v.w : expm1f(v.w);
            }
            *(float4*)&xs[r * XS_LD + c4 * 4] = v;
        }
        // stage W tile: KT x NT floats
#pragma unroll
        for (int i = 0; i < (KT * NT) / 1024; ++i) {
            int f = t + 256 * i;
            int r = f / (NT / 4);
            int c4 = f % (NT / 4);
            float4 v = *(const float4*)&W[(size_t)(kt + r) * NC + col0 + c4 * 4];
            *(float4*)&ws[r * NT + c4 * 4] = v;
        }
        __syncthreads();

#pragma unroll
        for (int k = 0; k < KT; ++k) {
            float4 wv = *(const float4*)&ws[k * NT + tx * 4];
#pragma unroll
            for (int i = 0; i < RT; ++i) {
                float xv = xs[(ty * RT + i) * XS_LD + k];
                acc[i][0] += xv * wv.x;
                acc[i][1] += xv * wv.y;
                acc[i][2] += xv * wv.z;
                acc[i][3] += xv * wv.w;
            }
        }
        __syncthreads();
    }

    float4 bv = make_float4(0.f, 0.f, 0.f, 0.f);
    if (BIAS) bv = *(const float4*)&bias[col0 + tx * 4];

#pragma unroll
    for (int i = 0; i < RT; ++i) {
        int gr = row0 + ty * RT + i;
        if (gr < nrows) {
            float4 o;
            o.x = acc[i][0] + bv.x;
            o.y = acc[i][1] + bv.y;
            o.z = acc[i][2] + bv.z;
            o.w = acc[i][3] + bv.w;
            if (ACT == 1) {
                o.x = (o.x > 0.f) ? o.x : 0.01f * o.x;
                o.y = (o.y > 0.f) ? o.y : 0.01f * o.y;
                o.z = (o.z > 0.f) ? o.z : 0.01f * o.z;
                o.w = (o.w > 0.f) ? o.w : 0.01f * o.w;
            }
            *(float4*)&Y[(size_t)gr * NC + col0 + tx * 4] = o;
        }
    }
}

// ---------------------------------------------------------------------------
// decoder: out[s] = dot32(tf[ts[s,0]], tg[ts[s,1]])   (8 lanes per sample)
// ---------------------------------------------------------------------------
__global__ void dot_kernel(const float* __restrict__ tf, const float* __restrict__ tg,
                           const int* __restrict__ ts, float* __restrict__ out, int m) {
    int gid = blockIdx.x * 256 + threadIdx.x;
    int s = gid >> 3;
    int l = gid & 7;
    if (s >= m) return;
    int ti = ts[2 * s + 0];
    int ui = ts[2 * s + 1];
    float4 a = ((const float4*)(tf + (size_t)ti * 32))[l];
    float4 b = ((const float4*)(tg + (size_t)ui * 32))[l];
    float d = a.x * b.x + a.y * b.y + a.z * b.z + a.w * b.w;
    d += __shfl_down(d, 4, 8);
    d += __shfl_down(d, 2, 8);
    d += __shfl_down(d, 1, 8);
    if (l == 0) out[s] = d;
}

// ---------------------------------------------------------------------------
extern "C" void kernel_launch(void* const* d_in, const int* in_sizes, int n_in,
                              void* d_out, int out_size, void* d_ws, size_t ws_size,
                              hipStream_t stream) {
    const float* x     = (const float*)d_in[0];
    const int*   ei    = (const int*)d_in[1];
    const int*   ts    = (const int*)d_in[2];
    const float* W1    = (const float*)d_in[3];
    const float* W2    = (const float*)d_in[4];
    const float* tf_w1 = (const float*)d_in[5];
    const float* tf_b1 = (const float*)d_in[6];
    const float* tf_w2 = (const float*)d_in[7];
    const float* tf_b2 = (const float*)d_in[8];
    const float* tg_w1 = (const float*)d_in[9];
    const float* tg_b1 = (const float*)d_in[10];
    const float* tg_w2 = (const float*)d_in[11];
    const float* tg_b2 = (const float*)d_in[12];
    float* out = (float*)d_out;

    const int n = in_sizes[0] / 256;   // 50000
    const int e = in_sizes[1] / 2;     // 640000
    const int m = in_sizes[2] / 2;     // 400000
    const int* src = ei;
    const int* dstp = ei + e;

    // workspace layout (4B units):
    //   dis[50176] | row_ptr[50176] | ideg/csr overlay [640064] | A | B | C
    // (ideg dead after scan_kernel; csr overlays it)
    float* wsf = (float*)d_ws;
    float* dis     = wsf;
    int*   row_ptr = (int*)(wsf + 50176);
    int*   ideg    = (int*)(wsf + 100352);
    int*   csr     = (int*)(wsf + 100352);
    float* A = wsf + 100352 + 640064;
    float* B = A + (size_t)n * 128;
    float* C = B + (size_t)n * 128;

    const int nb_n = (n + 255) / 256;
    const int nb_e = (e + 255) / 256;
    const int gy   = (n + 63) / 64;
    const int gg   = (n + 3) / 4;   // gather grid (4 waves/block)

    // 1) CSR build + normalization
    zero_ideg_kernel<<<nb_n, 256, 0, stream>>>(ideg, n);
    ideg_accum_kernel<<<nb_e, 256, 0, stream>>>(ideg, dstp, e);
    scan_kernel<<<1, 1024, 0, stream>>>(ideg, row_ptr, dis, n);
    fill_kernel<<<nb_e, 256, 0, stream>>>(src, dstp, row_ptr, csr, e);

    // 2) layer 1: A = x@W1 ; B = gather(A)
    gemm_kernel<256, 128, 64, 0, false, false><<<dim3(2, gy), 256, 0, stream>>>(x, W1, nullptr, A, n);
    gather_kernel<<<gg, 256, 0, stream>>>(A, row_ptr, csr, dis, B, n);

    // 3) layer 2: C = elu(B)@W2 ; A = gather(C)  (A = embed)
    gemm_kernel<128, 128, 64, 0, true, false><<<dim3(2, gy), 256, 0, stream>>>(B, W2, nullptr, C, n);
    gather_kernel<<<gg, 256, 0, stream>>>(C, row_ptr, csr, dis, A, n);

    // 4) heads
    float* tf1 = B;
    float* tg1 = B + (size_t)n * 64;
    float* tf2 = C;
    float* tg2 = C + (size_t)n * 32;
    gemm_kernel<128, 64, 64, 1, false, true><<<dim3(1, gy), 256, 0, stream>>>(A, tf_w1, tf_b1, tf1, n);
    gemm_kernel< 64, 32, 32, 1, false, true><<<dim3(1, gy), 256, 0, stream>>>(tf1, tf_w2, tf_b2, tf2, n);
    gemm_kernel<128, 64, 64, 1, false, true><<<dim3(1, gy), 256, 0, stream>>>(A, tg_w1, tg_b1, tg1, n);
    gemm_kernel< 64, 32, 32, 1, false, true><<<dim3(1, gy), 256, 0, stream>>>(tg1, tg_w2, tg_b2, tg2, n);

    // 5) decoder
    dot_kernel<<<(m * 8 + 255) / 256, 256, 0, stream>>>(tf2, tg2, ts, out, m);
}

// Round 5
// 751.462 us; speedup vs baseline: 2.9360x; 2.5544x over previous
//
#include <hip/hip_runtime.h>
#include <hip/hip_bf16.h>
#include <math.h>

// Problem constants: N=50000, E=640000, M=400000
// D_IN=256, H1=128, H2=128, H3=64, D_OUT=32
//
// Round 5: layer GEMMs -> bf16 MFMA (16x16x32) with 3-term compensated
// precision (Xh*Wh + Xl*Wh + Xh*Wl) so accuracy stays fp32-level.
// W1/W2 pre-converted + transposed to bf16 hi/lo once per launch.
// MFMA kernels have unique LDS size (73728) for profile attribution;
// head gemms are now the only 33792-LDS kernels.

typedef __attribute__((ext_vector_type(8))) short short8v;   // 8 bf16 (4 VGPR)
typedef __attribute__((ext_vector_type(4))) float f32x4;     // MFMA acc

__device__ inline unsigned short f2bf_rne(float f) {
    unsigned u = __float_as_uint(f);
    unsigned r = u + 0x7FFFu + ((u >> 16) & 1u);
    return (unsigned short)(r >> 16);
}
__device__ inline float bf2f(unsigned short h) {
    return __uint_as_float(((unsigned)h) << 16);
}

// ---------------------------------------------------------------------------
// CSR build + norm
// ---------------------------------------------------------------------------
__global__ void zero_ideg_kernel(int* __restrict__ ideg, int n) {
    int i = blockIdx.x * 256 + threadIdx.x;
    if (i < n) ideg[i] = 0;
}

__global__ void ideg_accum_kernel(int* __restrict__ ideg, const int* __restrict__ dst, int e) {
    int i = blockIdx.x * 256 + threadIdx.x;
    if (i < e) atomicAdd(&ideg[dst[i]], 1);
}

__global__ __launch_bounds__(1024) void scan_kernel(const int* __restrict__ ideg,
                                                    int* __restrict__ row_ptr,
                                                    float* __restrict__ dis, int n) {
    __shared__ int wsum[16];
    __shared__ int chunk_carry;
    const int tid = threadIdx.x;
    const int lane = tid & 63;
    const int wid = tid >> 6;
    if (tid == 0) chunk_carry = 0;
    __syncthreads();
    for (int base = 0; base < n; base += 1024) {
        int i = base + tid;
        int v = (i < n) ? ideg[i] : 0;
        if (i < n) dis[i] = rsqrtf(1.0f + (float)v);  // self-loop adds 1
        int incl = v;
#pragma unroll
        for (int off = 1; off < 64; off <<= 1) {
            int t = __shfl_up(incl, off, 64);
            if (lane >= off) incl += t;
        }
        if (lane == 63) wsum[wid] = incl;
        __syncthreads();
        if (wid == 0 && lane < 16) {
            int s = wsum[lane];
            int sc = s;
#pragma unroll
            for (int off = 1; off < 16; off <<= 1) {
                int t = __shfl_up(sc, off, 64);
                if (lane >= off) sc += t;
            }
            wsum[lane] = sc - s;
        }
        __syncthreads();
        int excl = chunk_carry + wsum[wid] + (incl - v);
        if (i < n) row_ptr[i] = excl;
        __syncthreads();
        if (tid == 1023) chunk_carry = excl + v;
        __syncthreads();
    }
    if (tid == 0) row_ptr[n] = chunk_carry;
}

__global__ void fill_kernel(const int* __restrict__ src, const int* __restrict__ dst,
                            int* __restrict__ row_ptr, int* __restrict__ csr, int e) {
    int i = blockIdx.x * 256 + threadIdx.x;
    if (i < e) {
        int d = dst[i];
        int pos = atomicAdd(&row_ptr[d], 1);
        csr[pos] = src[i];
    }
}

// ---------------------------------------------------------------------------
// W -> bf16 hi/lo, transposed: wt[c*K + k] = split(W[k*NC + c])
// ---------------------------------------------------------------------------
__global__ void convw_kernel(const float* __restrict__ W,
                             unsigned short* __restrict__ th, unsigned short* __restrict__ tl,
                             int K, int NC) {
    int id = blockIdx.x * 256 + threadIdx.x;
    if (id >= K * NC) return;
    int k = id / NC, c = id % NC;
    float w = W[id];
    unsigned short hb = f2bf_rne(w);
    unsigned short lb = f2bf_rne(w - bf2f(hb));
    th[c * K + k] = hb;
    tl[c * K + k] = lb;
}

// ---------------------------------------------------------------------------
// MFMA GEMM: Y[M,128] = X[M,K] @ W[K,128], 3-term compensated bf16.
// Tile 128 rows x 128 cols, BK=64, 256 threads (4 waves).
// Wave w owns rows [w*32, w*32+32): 2 row-frags x 8 col-frags of 16x16.
// Verified fragment layout (m89/m91): a lane l: A[row=l&15][k=(l>>4)*8+j];
// b lane l: B^T[col=l&15][k=(l>>4)*8+j]; C/D: col=l&15, row=(l>>4)*4+q.
// ---------------------------------------------------------------------------
template <int K, bool ELU_IN>
__global__ __launch_bounds__(256) void mfma_gemm_kernel(
    const float* __restrict__ X, const unsigned short* __restrict__ WTh,
    const unsigned short* __restrict__ WTl, float* __restrict__ Y, int nrows)
{
    constexpr int BK = 64;
    constexpr int LDA = BK + 8;  // 72 bf16 = 144B rows: banks advance 4/row -> <=2-way (free)
    __shared__ unsigned short Ah[128 * LDA];
    __shared__ unsigned short Al[128 * LDA];
    __shared__ unsigned short Bh[128 * LDA];
    __shared__ unsigned short Bl[128 * LDA];

    const int t = threadIdx.x;
    const int lane = t & 63;
    const int w = t >> 6;
    const int row0 = blockIdx.x * 128;

    f32x4 acc[2][8];
#pragma unroll
    for (int r = 0; r < 2; ++r)
#pragma unroll
        for (int c = 0; c < 8; ++c)
            acc[r][c] = (f32x4){0.f, 0.f, 0.f, 0.f};

    for (int kt = 0; kt < K; kt += BK) {
        // stage X tile: 128 rows x 64 k fp32 -> hi/lo bf16 (2048 float4, 8/thread)
#pragma unroll
        for (int i = 0; i < 8; ++i) {
            int f = t + 256 * i;
            int r = f >> 4;
            int c4 = f & 15;
            int gr = row0 + r;
            float4 v = make_float4(0.f, 0.f, 0.f, 0.f);
            if (gr < nrows) v = *(const float4*)&X[(size_t)gr * K + kt + c4 * 4];
            if (ELU_IN) {
                v.x = (v.x > 0.f) ? v.x : expm1f(v.x);
                v.y = (v.y > 0.f) ? v.y : expm1f(v.y);
                v.z = (v.z > 0.f) ? v.z : expm1f(v.z);
                v.w = (v.w > 0.f) ? v.w : expm1f(v.w);
            }
            unsigned short h0 = f2bf_rne(v.x), h1 = f2bf_rne(v.y),
                           h2 = f2bf_rne(v.z), h3 = f2bf_rne(v.w);
            ushort4 hv = make_ushort4(h0, h1, h2, h3);
            ushort4 lv = make_ushort4(f2bf_rne(v.x - bf2f(h0)), f2bf_rne(v.y - bf2f(h1)),
                                      f2bf_rne(v.z - bf2f(h2)), f2bf_rne(v.w - bf2f(h3)));
            *(ushort4*)&Ah[r * LDA + c4 * 4] = hv;
            *(ushort4*)&Al[r * LDA + c4 * 4] = lv;
        }
        // stage W tile: 128 cols x 64 k bf16 (1024 16B-chunks, 4/thread)
#pragma unroll
        for (int i = 0; i < 4; ++i) {
            int f = t + 256 * i;
            int col = f >> 3;
            int k8 = f & 7;
            *(uint4*)&Bh[col * LDA + k8 * 8] = *(const uint4*)&WTh[(size_t)col * K + kt + k8 * 8];
            *(uint4*)&Bl[col * LDA + k8 * 8] = *(const uint4*)&WTl[(size_t)col * K + kt + k8 * 8];
        }
        __syncthreads();

#pragma unroll
        for (int kk = 0; kk < BK; kk += 32) {
            const int koff = kk + (lane >> 4) * 8;
            short8v ah[2], al[2], bh[8], bl[8];
#pragma unroll
            for (int r = 0; r < 2; ++r) {
                int row = w * 32 + r * 16 + (lane & 15);
                ah[r] = *(const short8v*)&Ah[row * LDA + koff];
                al[r] = *(const short8v*)&Al[row * LDA + koff];
            }
#pragma unroll
            for (int c = 0; c < 8; ++c) {
                int col = c * 16 + (lane & 15);
                bh[c] = *(const short8v*)&Bh[col * LDA + koff];
                bl[c] = *(const short8v*)&Bl[col * LDA + koff];
            }
#pragma unroll
            for (int r = 0; r < 2; ++r)
#pragma unroll
                for (int c = 0; c < 8; ++c) {
                    acc[r][c] = __builtin_amdgcn_mfma_f32_16x16x32_bf16(ah[r], bh[c], acc[r][c], 0, 0, 0);
                    acc[r][c] = __builtin_amdgcn_mfma_f32_16x16x32_bf16(al[r], bh[c], acc[r][c], 0, 0, 0);
                    acc[r][c] = __builtin_amdgcn_mfma_f32_16x16x32_bf16(ah[r], bl[c], acc[r][c], 0, 0, 0);
                }
        }
        __syncthreads();
    }

    // epilogue: C/D layout col=lane&15, row=(lane>>4)*4+q
#pragma unroll
    for (int r = 0; r < 2; ++r)
#pragma unroll
        for (int c = 0; c < 8; ++c)
#pragma unroll
            for (int q = 0; q < 4; ++q) {
                int grow = row0 + w * 32 + r * 16 + (lane >> 4) * 4 + q;
                int gcol = c * 16 + (lane & 15);
                if (grow < nrows) Y[(size_t)grow * 128 + gcol] = acc[r][c][q];
            }
}

// ---------------------------------------------------------------------------
// Gather aggregation (unchanged): out[d,:] = dis[d]*(h[d]*dis[d] + sum h[s]*dis[s])
// ---------------------------------------------------------------------------
__global__ __launch_bounds__(256) void gather_kernel(const float* __restrict__ h,
                                                     const int* __restrict__ row_ptr,
                                                     const int* __restrict__ csr,
                                                     const float* __restrict__ dis,
                                                     float* __restrict__ outp, int n) {
    int node = blockIdx.x * 4 + (threadIdx.x >> 6);
    int lane = threadIdx.x & 63;
    if (node >= n) return;
    int beg = (node == 0) ? 0 : row_ptr[node - 1];
    int end = row_ptr[node];
    float dd = dis[node];
    const float2* h2 = (const float2*)h;
    float2 self = h2[(size_t)node * 64 + lane];
    float ax = self.x * dd;
    float ay = self.y * dd;
    int j = beg;
    for (; j + 4 <= end; j += 4) {
        int s0 = csr[j + 0], s1 = csr[j + 1], s2 = csr[j + 2], s3 = csr[j + 3];
        float d0 = dis[s0], d1 = dis[s1], d2 = dis[s2], d3 = dis[s3];
        float2 v0 = h2[(size_t)s0 * 64 + lane];
        float2 v1 = h2[(size_t)s1 * 64 + lane];
        float2 v2 = h2[(size_t)s2 * 64 + lane];
        float2 v3 = h2[(size_t)s3 * 64 + lane];
        ax += v0.x * d0 + v1.x * d1 + v2.x * d2 + v3.x * d3;
        ay += v0.y * d0 + v1.y * d1 + v2.y * d2 + v3.y * d3;
    }
    for (; j < end; ++j) {
        int s = csr[j];
        float ds = dis[s];
        float2 v = h2[(size_t)s * 64 + lane];
        ax += v.x * ds;
        ay += v.y * ds;
    }
    float2 o;
    o.x = ax * dd;
    o.y = ay * dd;
    ((float2*)outp)[(size_t)node * 64 + lane] = o;
}

// ---------------------------------------------------------------------------
// fp32 vector GEMM for the small heads (unchanged)
// ---------------------------------------------------------------------------
template <int K, int NC, int NT, int ACT, bool ELU_IN, bool BIAS>
__global__ __launch_bounds__(256, 4) void gemm_kernel(
    const float* __restrict__ X, const float* __restrict__ W,
    const float* __restrict__ bias, float* __restrict__ Y, int nrows)
{
    constexpr int KT = 64;
    constexpr int XS_LD = KT + 4;
    constexpr int CG = NT / 4;
    constexpr int RG = 256 / CG;
    constexpr int RT = 64 / RG;

    __shared__ float xs[64 * XS_LD];
    __shared__ float ws[KT * NT];

    const int t = threadIdx.x;
    const int tx = t % CG;
    const int ty = t / CG;
    const int row0 = blockIdx.y * 64;
    const int col0 = blockIdx.x * NT;

    float acc[RT][4];
#pragma unroll
    for (int i = 0; i < RT; ++i) {
        acc[i][0] = 0.f; acc[i][1] = 0.f; acc[i][2] = 0.f; acc[i][3] = 0.f;
    }

    for (int kt = 0; kt < K; kt += KT) {
#pragma unroll
        for (int i = 0; i < 4; ++i) {
            int f = t + 256 * i;
            int r = f >> 4;
            int c4 = f & 15;
            int gr = row0 + r;
            float4 v = make_float4(0.f, 0.f, 0.f, 0.f);
            if (gr < nrows) v = *(const float4*)&X[(size_t)gr * K + kt + c4 * 4];
            if (ELU_IN) {
                v.x = (v.x > 0.f) ? v.x : expm1f(v.x);
                v.y = (v.y > 0.f) ? v.y : expm1f(v.y);
                v.z = (v.z > 0.f) ? v.z : expm1f(v.z);
                v.w = (v.w > 0.f) ? v.w : expm1f(v.w);
            }
            *(float4*)&xs[r * XS_LD + c4 * 4] = v;
        }
#pragma unroll
        for (int i = 0; i < (KT * NT) / 1024; ++i) {
            int f = t + 256 * i;
            int r = f / (NT / 4);
            int c4 = f % (NT / 4);
            float4 v = *(const float4*)&W[(size_t)(kt + r) * NC + col0 + c4 * 4];
            *(float4*)&ws[r * NT + c4 * 4] = v;
        }
        __syncthreads();

#pragma unroll
        for (int k = 0; k < KT; ++k) {
            float4 wv = *(const float4*)&ws[k * NT + tx * 4];
#pragma unroll
            for (int i = 0; i < RT; ++i) {
                float xv = xs[(ty * RT + i) * XS_LD + k];
                acc[i][0] += xv * wv.x;
                acc[i][1] += xv * wv.y;
                acc[i][2] += xv * wv.z;
                acc[i][3] += xv * wv.w;
            }
        }
        __syncthreads();
    }

    float4 bv = make_float4(0.f, 0.f, 0.f, 0.f);
    if (BIAS) bv = *(const float4*)&bias[col0 + tx * 4];

#pragma unroll
    for (int i = 0; i < RT; ++i) {
        int gr = row0 + ty * RT + i;
        if (gr < nrows) {
            float4 o;
            o.x = acc[i][0] + bv.x;
            o.y = acc[i][1] + bv.y;
            o.z = acc[i][2] + bv.z;
            o.w = acc[i][3] + bv.w;
            if (ACT == 1) {
                o.x = (o.x > 0.f) ? o.x : 0.01f * o.x;
                o.y = (o.y > 0.f) ? o.y : 0.01f * o.y;
                o.z = (o.z > 0.f) ? o.z : 0.01f * o.z;
                o.w = (o.w > 0.f) ? o.w : 0.01f * o.w;
            }
            *(float4*)&Y[(size_t)gr * NC + col0 + tx * 4] = o;
        }
    }
}

// ---------------------------------------------------------------------------
// decoder (unchanged)
// ---------------------------------------------------------------------------
__global__ void dot_kernel(const float* __restrict__ tf, const float* __restrict__ tg,
                           const int* __restrict__ ts, float* __restrict__ out, int m) {
    int gid = blockIdx.x * 256 + threadIdx.x;
    int s = gid >> 3;
    int l = gid & 7;
    if (s >= m) return;
    int ti = ts[2 * s + 0];
    int ui = ts[2 * s + 1];
    float4 a = ((const float4*)(tf + (size_t)ti * 32))[l];
    float4 b = ((const float4*)(tg + (size_t)ui * 32))[l];
    float d = a.x * b.x + a.y * b.y + a.z * b.z + a.w * b.w;
    d += __shfl_down(d, 4, 8);
    d += __shfl_down(d, 2, 8);
    d += __shfl_down(d, 1, 8);
    if (l == 0) out[s] = d;
}

// ---------------------------------------------------------------------------
extern "C" void kernel_launch(void* const* d_in, const int* in_sizes, int n_in,
                              void* d_out, int out_size, void* d_ws, size_t ws_size,
                              hipStream_t stream) {
    const float* x     = (const float*)d_in[0];
    const int*   ei    = (const int*)d_in[1];
    const int*   ts    = (const int*)d_in[2];
    const float* W1    = (const float*)d_in[3];
    const float* W2    = (const float*)d_in[4];
    const float* tf_w1 = (const float*)d_in[5];
    const float* tf_b1 = (const float*)d_in[6];
    const float* tf_w2 = (const float*)d_in[7];
    const float* tf_b2 = (const float*)d_in[8];
    const float* tg_w1 = (const float*)d_in[9];
    const float* tg_b1 = (const float*)d_in[10];
    const float* tg_w2 = (const float*)d_in[11];
    const float* tg_b2 = (const float*)d_in[12];
    float* out = (float*)d_out;

    const int n = in_sizes[0] / 256;   // 50000
    const int e = in_sizes[1] / 2;     // 640000
    const int m = in_sizes[2] / 2;     // 400000
    const int* src = ei;
    const int* dstp = ei + e;

    // workspace layout (4B units):
    //   dis[50176] | row_ptr[50176] | ideg/csr[640064] |
    //   w1th[16384] w1tl[16384] w2th[8192] w2tl[8192] | A | B | C
    float* wsf = (float*)d_ws;
    float* dis     = wsf;
    int*   row_ptr = (int*)(wsf + 50176);
    int*   ideg    = (int*)(wsf + 100352);
    int*   csr     = (int*)(wsf + 100352);
    unsigned short* w1th = (unsigned short*)(wsf + 740416);
    unsigned short* w1tl = (unsigned short*)(wsf + 740416 + 16384);
    unsigned short* w2th = (unsigned short*)(wsf + 740416 + 32768);
    unsigned short* w2tl = (unsigned short*)(wsf + 740416 + 40960);
    float* A = wsf + 740416 + 49152;
    float* B = A + (size_t)n * 128;
    float* C = B + (size_t)n * 128;

    const int nb_n = (n + 255) / 256;
    const int nb_e = (e + 255) / 256;
    const int gy   = (n + 63) / 64;
    const int gg   = (n + 3) / 4;
    const int gm   = (n + 127) / 128;  // MFMA gemm grid: 391

    // 1) CSR build + normalization
    zero_ideg_kernel<<<nb_n, 256, 0, stream>>>(ideg, n);
    ideg_accum_kernel<<<nb_e, 256, 0, stream>>>(ideg, dstp, e);
    scan_kernel<<<1, 1024, 0, stream>>>(ideg, row_ptr, dis, n);
    fill_kernel<<<nb_e, 256, 0, stream>>>(src, dstp, row_ptr, csr, e);

    // 1b) weight conversion (bf16 hi/lo, transposed)
    convw_kernel<<<(256 * 128 + 255) / 256, 256, 0, stream>>>(W1, w1th, w1tl, 256, 128);
    convw_kernel<<<(128 * 128 + 255) / 256, 256, 0, stream>>>(W2, w2th, w2tl, 128, 128);

    // 2) layer 1: A = x@W1 (MFMA) ; B = gather(A)
    mfma_gemm_kernel<256, false><<<gm, 256, 0, stream>>>(x, w1th, w1tl, A, n);
    gather_kernel<<<gg, 256, 0, stream>>>(A, row_ptr, csr, dis, B, n);

    // 3) layer 2: C = elu(B)@W2 (MFMA) ; A = gather(C)  (A = embed)
    mfma_gemm_kernel<128, true><<<gm, 256, 0, stream>>>(B, w2th, w2tl, C, n);
    gather_kernel<<<gg, 256, 0, stream>>>(C, row_ptr, csr, dis, A, n);

    // 4) heads
    float* tf1 = B;
    float* tg1 = B + (size_t)n * 64;
    float* tf2 = C;
    float* tg2 = C + (size_t)n * 32;
    gemm_kernel<128, 64, 64, 1, false, true><<<dim3(1, gy), 256, 0, stream>>>(A, tf_w1, tf_b1, tf1, n);
    gemm_kernel< 64, 32, 32, 1, false, true><<<dim3(1, gy), 256, 0, stream>>>(tf1, tf_w2, tf_b2, tf2, n);
    gemm_kernel<128, 64, 64, 1, false, true><<<dim3(1, gy), 256, 0, stream>>>(A, tg_w1, tg_b1, tg1, n);
    gemm_kernel< 64, 32, 32, 1, false, true><<<dim3(1, gy), 256, 0, stream>>>(tg1, tg_w2, tg_b2, tg2, n);

    // 5) decoder
    dot_kernel<<<(m * 8 + 255) / 256, 256, 0, stream>>>(tf2, tg2, ts, out, m);
}

// Round 6
// 465.482 us; speedup vs baseline: 4.7398x; 1.6144x over previous
//
#include <hip/hip_runtime.h>
#include <hip/hip_bf16.h>
#include <math.h>

// Problem constants: N=50000, E=640000, M=400000
// D_IN=256, H1=128, H2=128, H3=64, D_OUT=32
//
// Round 6: heads -> 2 fused MFMA gemms (cat-weight head1, block-diag head2),
// all weight prep in one kernel. fp32 head gemms (the 25600-LDS top-5
// windows) deleted. Layers/gather/CSR unchanged from round 5.

typedef __attribute__((ext_vector_type(8))) short short8v;   // 8 bf16 (4 VGPR)
typedef __attribute__((ext_vector_type(4))) float f32x4;     // MFMA acc

__device__ inline unsigned short f2bf_rne(float f) {
    unsigned u = __float_as_uint(f);
    unsigned r = u + 0x7FFFu + ((u >> 16) & 1u);
    return (unsigned short)(r >> 16);
}
__device__ inline float bf2f(unsigned short h) {
    return __uint_as_float(((unsigned)h) << 16);
}

// ---------------------------------------------------------------------------
// CSR build + norm (unchanged)
// ---------------------------------------------------------------------------
__global__ void zero_ideg_kernel(int* __restrict__ ideg, int n) {
    int i = blockIdx.x * 256 + threadIdx.x;
    if (i < n) ideg[i] = 0;
}

__global__ void ideg_accum_kernel(int* __restrict__ ideg, const int* __restrict__ dst, int e) {
    int i = blockIdx.x * 256 + threadIdx.x;
    if (i < e) atomicAdd(&ideg[dst[i]], 1);
}

__global__ __launch_bounds__(1024) void scan_kernel(const int* __restrict__ ideg,
                                                    int* __restrict__ row_ptr,
                                                    float* __restrict__ dis, int n) {
    __shared__ int wsum[16];
    __shared__ int chunk_carry;
    const int tid = threadIdx.x;
    const int lane = tid & 63;
    const int wid = tid >> 6;
    if (tid == 0) chunk_carry = 0;
    __syncthreads();
    for (int base = 0; base < n; base += 1024) {
        int i = base + tid;
        int v = (i < n) ? ideg[i] : 0;
        if (i < n) dis[i] = rsqrtf(1.0f + (float)v);  // self-loop adds 1
        int incl = v;
#pragma unroll
        for (int off = 1; off < 64; off <<= 1) {
            int t = __shfl_up(incl, off, 64);
            if (lane >= off) incl += t;
        }
        if (lane == 63) wsum[wid] = incl;
        __syncthreads();
        if (wid == 0 && lane < 16) {
            int s = wsum[lane];
            int sc = s;
#pragma unroll
            for (int off = 1; off < 16; off <<= 1) {
                int t = __shfl_up(sc, off, 64);
                if (lane >= off) sc += t;
            }
            wsum[lane] = sc - s;
        }
        __syncthreads();
        int excl = chunk_carry + wsum[wid] + (incl - v);
        if (i < n) row_ptr[i] = excl;
        __syncthreads();
        if (tid == 1023) chunk_carry = excl + v;
        __syncthreads();
    }
    if (tid == 0) row_ptr[n] = chunk_carry;
}

__global__ void fill_kernel(const int* __restrict__ src, const int* __restrict__ dst,
                            int* __restrict__ row_ptr, int* __restrict__ csr, int e) {
    int i = blockIdx.x * 256 + threadIdx.x;
    if (i < e) {
        int d = dst[i];
        int pos = atomicAdd(&row_ptr[d], 1);
        csr[pos] = src[i];
    }
}

// ---------------------------------------------------------------------------
// One-shot weight prep: all transposed hi/lo bf16 splits + concatenated biases.
//   w1t : [128 cols][K=256]  from W1 (256x128)
//   w2t : [128 cols][K=128]  from W2 (128x128)
//   h1t : [128 cols][K=128]  from [tf_w1 | tg_w1]  (128x64 each)
//   h2t : [ 64 cols][K=128]  block-diag: tf_w2 (64x32) on TL, tg_w2 on BR
//   bcat1[128] = [tf_b1 | tg_b1], bcat2[64] = [tf_b2 | tg_b2]
// ---------------------------------------------------------------------------
__global__ void prep_weights_kernel(
    const float* __restrict__ W1, const float* __restrict__ W2,
    const float* __restrict__ tfw1, const float* __restrict__ tfb1,
    const float* __restrict__ tfw2, const float* __restrict__ tfb2,
    const float* __restrict__ tgw1, const float* __restrict__ tgb1,
    const float* __restrict__ tgw2, const float* __restrict__ tgb2,
    unsigned short* __restrict__ w1th, unsigned short* __restrict__ w1tl,
    unsigned short* __restrict__ w2th, unsigned short* __restrict__ w2tl,
    unsigned short* __restrict__ h1th, unsigned short* __restrict__ h1tl,
    unsigned short* __restrict__ h2th, unsigned short* __restrict__ h2tl,
    float* __restrict__ bcat1, float* __restrict__ bcat2)
{
    int id = blockIdx.x * 256 + threadIdx.x;
    float w;
    unsigned short* th;
    unsigned short* tl;
    int idx;
    if (id < 32768) {                       // W1: [256][128]
        int k = id >> 7, c = id & 127;
        w = W1[id]; th = w1th; tl = w1tl; idx = c * 256 + k;
    } else if (id < 49152) {                // W2: [128][128]
        int j = id - 32768;
        int k = j >> 7, c = j & 127;
        w = W2[j]; th = w2th; tl = w2tl; idx = c * 128 + k;
    } else if (id < 65536) {                // H1 cat: [128][128]
        int j = id - 49152;
        int k = j >> 7, c = j & 127;
        w = (c < 64) ? tfw1[k * 64 + c] : tgw1[k * 64 + (c - 64)];
        th = h1th; tl = h1tl; idx = c * 128 + k;
    } else if (id < 73728) {                // H2 block-diag: [128][64]
        int j = id - 65536;
        int k = j >> 6, c = j & 63;
        w = 0.f;
        if (k < 64 && c < 32) w = tfw2[k * 32 + c];
        else if (k >= 64 && c >= 32) w = tgw2[(k - 64) * 32 + (c - 32)];
        th = h2th; tl = h2tl; idx = c * 128 + k;
    } else if (id < 73856) {
        int c = id - 73728;
        bcat1[c] = (c < 64) ? tfb1[c] : tgb1[c - 64];
        return;
    } else if (id < 73920) {
        int c = id - 73856;
        bcat2[c] = (c < 32) ? tfb2[c] : tgb2[c - 32];
        return;
    } else {
        return;
    }
    unsigned short hb = f2bf_rne(w);
    th[idx] = hb;
    tl[idx] = f2bf_rne(w - bf2f(hb));
}

// ---------------------------------------------------------------------------
// MFMA GEMM: Y[M,NCOL] = act( X[M,K] @ W[K,NCOL] + bias ), 3-term compensated.
// Tile 128 rows x NCOL cols, BK=64, 256 threads (4 waves).
// Fragment layouts per m89/m91 (verified): A lane l holds row=l&15,
// k=(l>>4)*8+j; B^T lane l: col=l&15, same k; C/D: col=l&15, row=(l>>4)*4+q.
// ---------------------------------------------------------------------------
template <int K, int NCOL, bool ELU_IN, bool LRELU, bool BIAS>
__global__ __launch_bounds__(256) void mfma_gemm_kernel(
    const float* __restrict__ X, const unsigned short* __restrict__ WTh,
    const unsigned short* __restrict__ WTl, const float* __restrict__ bias,
    float* __restrict__ Y, int nrows)
{
    constexpr int BK = 64;
    constexpr int LDA = BK + 8;  // 72 bf16 rows = 144B: <=2-way bank alias (free)
    constexpr int NF = NCOL / 16;
    __shared__ unsigned short Ah[128 * LDA];
    __shared__ unsigned short Al[128 * LDA];
    __shared__ unsigned short Bh[NCOL * LDA];
    __shared__ unsigned short Bl[NCOL * LDA];

    const int t = threadIdx.x;
    const int lane = t & 63;
    const int w = t >> 6;
    const int row0 = blockIdx.x * 128;

    f32x4 acc[2][NF];
#pragma unroll
    for (int r = 0; r < 2; ++r)
#pragma unroll
        for (int c = 0; c < NF; ++c)
            acc[r][c] = (f32x4){0.f, 0.f, 0.f, 0.f};

    for (int kt = 0; kt < K; kt += BK) {
        // stage X tile: 128 rows x 64 k fp32 -> hi/lo bf16 (2048 float4, 8/thread)
#pragma unroll
        for (int i = 0; i < 8; ++i) {
            int f = t + 256 * i;
            int r = f >> 4;
            int c4 = f & 15;
            int gr = row0 + r;
            float4 v = make_float4(0.f, 0.f, 0.f, 0.f);
            if (gr < nrows) v = *(const float4*)&X[(size_t)gr * K + kt + c4 * 4];
            if (ELU_IN) {
                v.x = (v.x > 0.f) ? v.x : expm1f(v.x);
                v.y = (v.y > 0.f) ? v.y : expm1f(v.y);
                v.z = (v.z > 0.f) ? v.z : expm1f(v.z);
                v.w = (v.w > 0.f) ? v.w : expm1f(v.w);
            }
            unsigned short h0 = f2bf_rne(v.x), h1 = f2bf_rne(v.y),
                           h2 = f2bf_rne(v.z), h3 = f2bf_rne(v.w);
            ushort4 hv = make_ushort4(h0, h1, h2, h3);
            ushort4 lv = make_ushort4(f2bf_rne(v.x - bf2f(h0)), f2bf_rne(v.y - bf2f(h1)),
                                      f2bf_rne(v.z - bf2f(h2)), f2bf_rne(v.w - bf2f(h3)));
            *(ushort4*)&Ah[r * LDA + c4 * 4] = hv;
            *(ushort4*)&Al[r * LDA + c4 * 4] = lv;
        }
        // stage W tile: NCOL cols x 64 k bf16 (NCOL*8 16B-chunks, NCOL/32 per thread)
#pragma unroll
        for (int i = 0; i < NCOL / 32; ++i) {
            int f = t + 256 * i;
            int col = f >> 3;
            int k8 = f & 7;
            *(uint4*)&Bh[col * LDA + k8 * 8] = *(const uint4*)&WTh[(size_t)col * K + kt + k8 * 8];
            *(uint4*)&Bl[col * LDA + k8 * 8] = *(const uint4*)&WTl[(size_t)col * K + kt + k8 * 8];
        }
        __syncthreads();

#pragma unroll
        for (int kk = 0; kk < BK; kk += 32) {
            const int koff = kk + (lane >> 4) * 8;
            short8v ah[2], al[2], bh[NF], bl[NF];
#pragma unroll
            for (int r = 0; r < 2; ++r) {
                int row = w * 32 + r * 16 + (lane & 15);
                ah[r] = *(const short8v*)&Ah[row * LDA + koff];
                al[r] = *(const short8v*)&Al[row * LDA + koff];
            }
#pragma unroll
            for (int c = 0; c < NF; ++c) {
                int col = c * 16 + (lane & 15);
                bh[c] = *(const short8v*)&Bh[col * LDA + koff];
                bl[c] = *(const short8v*)&Bl[col * LDA + koff];
            }
#pragma unroll
            for (int r = 0; r < 2; ++r)
#pragma unroll
                for (int c = 0; c < NF; ++c) {
                    acc[r][c] = __builtin_amdgcn_mfma_f32_16x16x32_bf16(ah[r], bh[c], acc[r][c], 0, 0, 0);
                    acc[r][c] = __builtin_amdgcn_mfma_f32_16x16x32_bf16(al[r], bh[c], acc[r][c], 0, 0, 0);
                    acc[r][c] = __builtin_amdgcn_mfma_f32_16x16x32_bf16(ah[r], bl[c], acc[r][c], 0, 0, 0);
                }
        }
        __syncthreads();
    }

    // epilogue: C/D layout col=lane&15, row=(lane>>4)*4+q
#pragma unroll
    for (int c = 0; c < NF; ++c) {
        int gcol = c * 16 + (lane & 15);
        float bv = BIAS ? bias[gcol] : 0.f;
#pragma unroll
        for (int r = 0; r < 2; ++r)
#pragma unroll
            for (int q = 0; q < 4; ++q) {
                int grow = row0 + w * 32 + r * 16 + (lane >> 4) * 4 + q;
                if (grow < nrows) {
                    float o = acc[r][c][q] + bv;
                    if (LRELU) o = (o > 0.f) ? o : 0.01f * o;
                    Y[(size_t)grow * NCOL + gcol] = o;
                }
            }
    }
}

// ---------------------------------------------------------------------------
// Gather aggregation (unchanged): out[d,:] = dis[d]*(h[d]*dis[d] + sum h[s]*dis[s])
// ---------------------------------------------------------------------------
__global__ __launch_bounds__(256) void gather_kernel(const float* __restrict__ h,
                                                     const int* __restrict__ row_ptr,
                                                     const int* __restrict__ csr,
                                                     const float* __restrict__ dis,
                                                     float* __restrict__ outp, int n) {
    int node = blockIdx.x * 4 + (threadIdx.x >> 6);
    int lane = threadIdx.x & 63;
    if (node >= n) return;
    int beg = (node == 0) ? 0 : row_ptr[node - 1];
    int end = row_ptr[node];
    float dd = dis[node];
    const float2* h2 = (const float2*)h;
    float2 self = h2[(size_t)node * 64 + lane];
    float ax = self.x * dd;
    float ay = self.y * dd;
    int j = beg;
    for (; j + 4 <= end; j += 4) {
        int s0 = csr[j + 0], s1 = csr[j + 1], s2 = csr[j + 2], s3 = csr[j + 3];
        float d0 = dis[s0], d1 = dis[s1], d2 = dis[s2], d3 = dis[s3];
        float2 v0 = h2[(size_t)s0 * 64 + lane];
        float2 v1 = h2[(size_t)s1 * 64 + lane];
        float2 v2 = h2[(size_t)s2 * 64 + lane];
        float2 v3 = h2[(size_t)s3 * 64 + lane];
        ax += v0.x * d0 + v1.x * d1 + v2.x * d2 + v3.x * d3;
        ay += v0.y * d0 + v1.y * d1 + v2.y * d2 + v3.y * d3;
    }
    for (; j < end; ++j) {
        int s = csr[j];
        float ds = dis[s];
        float2 v = h2[(size_t)s * 64 + lane];
        ax += v.x * ds;
        ay += v.y * ds;
    }
    float2 o;
    o.x = ax * dd;
    o.y = ay * dd;
    ((float2*)outp)[(size_t)node * 64 + lane] = o;
}

// ---------------------------------------------------------------------------
// decoder: Z layout [node][64] = [tf2(32) | tg2(32)]; 8 lanes per sample
// ---------------------------------------------------------------------------
__global__ void dot_kernel(const float* __restrict__ Z,
                           const int* __restrict__ ts, float* __restrict__ out, int m) {
    int gid = blockIdx.x * 256 + threadIdx.x;
    int s = gid >> 3;
    int l = gid & 7;
    if (s >= m) return;
    int ti = ts[2 * s + 0];
    int ui = ts[2 * s + 1];
    float4 a = *(const float4*)&Z[(size_t)ti * 64 + l * 4];
    float4 b = *(const float4*)&Z[(size_t)ui * 64 + 32 + l * 4];
    float d = a.x * b.x + a.y * b.y + a.z * b.z + a.w * b.w;
    d += __shfl_down(d, 4, 8);
    d += __shfl_down(d, 2, 8);
    d += __shfl_down(d, 1, 8);
    if (l == 0) out[s] = d;
}

// ---------------------------------------------------------------------------
extern "C" void kernel_launch(void* const* d_in, const int* in_sizes, int n_in,
                              void* d_out, int out_size, void* d_ws, size_t ws_size,
                              hipStream_t stream) {
    const float* x     = (const float*)d_in[0];
    const int*   ei    = (const int*)d_in[1];
    const int*   ts    = (const int*)d_in[2];
    const float* W1    = (const float*)d_in[3];
    const float* W2    = (const float*)d_in[4];
    const float* tf_w1 = (const float*)d_in[5];
    const float* tf_b1 = (const float*)d_in[6];
    const float* tf_w2 = (const float*)d_in[7];
    const float* tf_b2 = (const float*)d_in[8];
    const float* tg_w1 = (const float*)d_in[9];
    const float* tg_b1 = (const float*)d_in[10];
    const float* tg_w2 = (const float*)d_in[11];
    const float* tg_b2 = (const float*)d_in[12];
    float* out = (float*)d_out;

    const int n = in_sizes[0] / 256;   // 50000
    const int e = in_sizes[1] / 2;     // 640000
    const int m = in_sizes[2] / 2;     // 400000
    const int* src = ei;
    const int* dstp = ei + e;

    // workspace layout (4B units):
    //   dis[50176] | row_ptr[50176] | ideg/csr[640064] | weights[73920+pad] | A | B | C
    float* wsf = (float*)d_ws;
    float* dis     = wsf;
    int*   row_ptr = (int*)(wsf + 50176);
    int*   ideg    = (int*)(wsf + 100352);
    int*   csr     = (int*)(wsf + 100352);
    const int WB = 740416;
    unsigned short* w1th = (unsigned short*)(wsf + WB);            // 16384 fu
    unsigned short* w1tl = (unsigned short*)(wsf + WB + 16384);
    unsigned short* w2th = (unsigned short*)(wsf + WB + 32768);    // 8192 fu
    unsigned short* w2tl = (unsigned short*)(wsf + WB + 40960);
    unsigned short* h1th = (unsigned short*)(wsf + WB + 49152);    // 8192 fu
    unsigned short* h1tl = (unsigned short*)(wsf + WB + 57344);
    unsigned short* h2th = (unsigned short*)(wsf + WB + 65536);    // 4096 fu
    unsigned short* h2tl = (unsigned short*)(wsf + WB + 69632);
    float* bcat1 = wsf + WB + 73728;                               // 128 fu
    float* bcat2 = wsf + WB + 73856;                               // 64 fu
    float* A = wsf + WB + 73984;
    float* B = A + (size_t)n * 128;
    float* C = B + (size_t)n * 128;

    const int nb_n = (n + 255) / 256;
    const int nb_e = (e + 255) / 256;
    const int gg   = (n + 3) / 4;      // gather grid
    const int gm   = (n + 127) / 128;  // MFMA grid: 391

    // 1) CSR build + normalization
    zero_ideg_kernel<<<nb_n, 256, 0, stream>>>(ideg, n);
    ideg_accum_kernel<<<nb_e, 256, 0, stream>>>(ideg, dstp, e);
    scan_kernel<<<1, 1024, 0, stream>>>(ideg, row_ptr, dis, n);
    fill_kernel<<<nb_e, 256, 0, stream>>>(src, dstp, row_ptr, csr, e);

    // 1b) all weight prep in one kernel (73920 ids)
    prep_weights_kernel<<<(73920 + 255) / 256, 256, 0, stream>>>(
        W1, W2, tf_w1, tf_b1, tf_w2, tf_b2, tg_w1, tg_b1, tg_w2, tg_b2,
        w1th, w1tl, w2th, w2tl, h1th, h1tl, h2th, h2tl, bcat1, bcat2);

    // 2) layer 1: A = x@W1 ; B = gather(A)
    mfma_gemm_kernel<256, 128, false, false, false><<<gm, 256, 0, stream>>>(x, w1th, w1tl, nullptr, A, n);
    gather_kernel<<<gg, 256, 0, stream>>>(A, row_ptr, csr, dis, B, n);

    // 3) layer 2: C = elu(B)@W2 ; A = gather(C)  (A = embed)
    mfma_gemm_kernel<128, 128, true, false, false><<<gm, 256, 0, stream>>>(B, w2th, w2tl, nullptr, C, n);
    gather_kernel<<<gg, 256, 0, stream>>>(C, row_ptr, csr, dis, A, n);

    // 4) heads: B = lrelu(A@[tf_w1|tg_w1]+bcat1) ; C = lrelu(B@blockdiag+bcat2)
    mfma_gemm_kernel<128, 128, false, true, true><<<gm, 256, 0, stream>>>(A, h1th, h1tl, bcat1, B, n);
    mfma_gemm_kernel<128, 64, false, true, true><<<gm, 256, 0, stream>>>(B, h2th, h2tl, bcat2, C, n);

    // 5) decoder
    dot_kernel<<<(m * 8 + 255) / 256, 256, 0, stream>>>(C, ts, out, m);
}

// Round 7
// 404.941 us; speedup vs baseline: 5.4484x; 1.1495x over previous
//
#include <hip/hip_runtime.h>
#include <hip/hip_bf16.h>
#include <math.h>

// Problem constants: N=50000, E=640000, M=400000
// D_IN=256, H1=128, H2=128, H3=64, D_OUT=32
//
// Round 7: MFMA gemm goes LDS-free. prep_weights emits W in MFMA fragment
// order ([kk][colfrag][hi/lo][lane][8]) -> B frags are coalesced wave-uniform
// global loads (L1-broadcast). A frags load straight from global X, fp32->
// bf16 hi/lo split in registers. 16 rows/wave, 64 rows/block, grid 782,
// no __shared__, no barriers, no bank conflicts.
// Gather: 32 lanes/node + float4 (2 node-chains/wave for MLP).

typedef __attribute__((ext_vector_type(8))) short short8v;   // 8 bf16 (4 VGPR)
typedef __attribute__((ext_vector_type(4))) float f32x4;     // MFMA acc

__device__ inline unsigned short f2bf_rne(float f) {
    unsigned u = __float_as_uint(f);
    unsigned r = u + 0x7FFFu + ((u >> 16) & 1u);
    return (unsigned short)(r >> 16);
}
__device__ inline float bf2f(unsigned short h) {
    return __uint_as_float(((unsigned)h) << 16);
}

// ---------------------------------------------------------------------------
// CSR build + norm (unchanged)
// ---------------------------------------------------------------------------
__global__ void zero_ideg_kernel(int* __restrict__ ideg, int n) {
    int i = blockIdx.x * 256 + threadIdx.x;
    if (i < n) ideg[i] = 0;
}

__global__ void ideg_accum_kernel(int* __restrict__ ideg, const int* __restrict__ dst, int e) {
    int i = blockIdx.x * 256 + threadIdx.x;
    if (i < e) atomicAdd(&ideg[dst[i]], 1);
}

__global__ __launch_bounds__(1024) void scan_kernel(const int* __restrict__ ideg,
                                                    int* __restrict__ row_ptr,
                                                    float* __restrict__ dis, int n) {
    __shared__ int wsum[16];
    __shared__ int chunk_carry;
    const int tid = threadIdx.x;
    const int lane = tid & 63;
    const int wid = tid >> 6;
    if (tid == 0) chunk_carry = 0;
    __syncthreads();
    for (int base = 0; base < n; base += 1024) {
        int i = base + tid;
        int v = (i < n) ? ideg[i] : 0;
        if (i < n) dis[i] = rsqrtf(1.0f + (float)v);  // self-loop adds 1
        int incl = v;
#pragma unroll
        for (int off = 1; off < 64; off <<= 1) {
            int t = __shfl_up(incl, off, 64);
            if (lane >= off) incl += t;
        }
        if (lane == 63) wsum[wid] = incl;
        __syncthreads();
        if (wid == 0 && lane < 16) {
            int s = wsum[lane];
            int sc = s;
#pragma unroll
            for (int off = 1; off < 16; off <<= 1) {
                int t = __shfl_up(sc, off, 64);
                if (lane >= off) sc += t;
            }
            wsum[lane] = sc - s;
        }
        __syncthreads();
        int excl = chunk_carry + wsum[wid] + (incl - v);
        if (i < n) row_ptr[i] = excl;
        __syncthreads();
        if (tid == 1023) chunk_carry = excl + v;
        __syncthreads();
    }
    if (tid == 0) row_ptr[n] = chunk_carry;
}

__global__ void fill_kernel(const int* __restrict__ src, const int* __restrict__ dst,
                            int* __restrict__ row_ptr, int* __restrict__ csr, int e) {
    int i = blockIdx.x * 256 + threadIdx.x;
    if (i < e) {
        int d = dst[i];
        int pos = atomicAdd(&row_ptr[d], 1);
        csr[pos] = src[i];
    }
}

// ---------------------------------------------------------------------------
// Weight prep in MFMA-fragment order.
// Fragment layout (shorts): id = ((kk*NF + c)*2 + h)*512 + lane*8 + j
//   k = kk*32 + (lane>>4)*8 + j ; col = c*16 + (lane&15) ; h: 0=hi 1=lo
// Ranges (shorts): W1f 65536 | W2f 32768 | H1f 32768 | H2f 16384 = 147456
// then bcat1[128], bcat2[64] (floats).
// ---------------------------------------------------------------------------
__global__ void prep_weights_kernel(
    const float* __restrict__ W1, const float* __restrict__ W2,
    const float* __restrict__ tfw1, const float* __restrict__ tfb1,
    const float* __restrict__ tfw2, const float* __restrict__ tfb2,
    const float* __restrict__ tgw1, const float* __restrict__ tgb1,
    const float* __restrict__ tgw2, const float* __restrict__ tgb2,
    unsigned short* __restrict__ wf,   // all four frag arrays, contiguous
    float* __restrict__ bcat1, float* __restrict__ bcat2)
{
    int id = blockIdx.x * 256 + threadIdx.x;
    if (id >= 147456) {
        if (id < 147456 + 128) {
            int c = id - 147456;
            bcat1[c] = (c < 64) ? tfb1[c] : tgb1[c - 64];
        } else if (id < 147456 + 192) {
            int c = id - 147456 - 128;
            bcat2[c] = (c < 32) ? tfb2[c] : tgb2[c - 32];
        }
        return;
    }
    int base, NF;
    const int local = id;
    int lid;
    if (id < 65536)       { base = 0;      NF = 8; lid = local; }
    else if (id < 98304)  { base = 65536;  NF = 8; lid = local - 65536; }
    else if (id < 131072) { base = 98304;  NF = 8; lid = local - 98304; }
    else                  { base = 131072; NF = 4; lid = local - 131072; }

    int j    = lid & 7;
    int lane = (lid >> 3) & 63;
    int h    = (lid >> 9) & 1;
    int rest = lid >> 10;
    int c    = rest % NF;
    int kk   = rest / NF;
    int k    = kk * 32 + (lane >> 4) * 8 + j;
    int col  = c * 16 + (lane & 15);

    float w;
    if (id < 65536) {                 // W1: [256][128]
        w = W1[k * 128 + col];
    } else if (id < 98304) {          // W2: [128][128]
        w = W2[k * 128 + col];
    } else if (id < 131072) {         // H1 cat: [128][128] = [tf_w1 | tg_w1]
        w = (col < 64) ? tfw1[k * 64 + col] : tgw1[k * 64 + (col - 64)];
    } else {                          // H2 block-diag: [128][64]
        w = 0.f;
        if (k < 64 && col < 32) w = tfw2[k * 32 + col];
        else if (k >= 64 && col >= 32) w = tgw2[(k - 64) * 32 + (col - 32)];
    }
    unsigned short hb = f2bf_rne(w);
    wf[base + lid] = h ? f2bf_rne(w - bf2f(hb)) : hb;
}

// ---------------------------------------------------------------------------
// LDS-free MFMA GEMM: Y[M,NCOL] = act( X[M,K] @ W + bias ), 3-term compensated.
// 16 rows/wave, 4 waves/block (64 rows). B frags: wave-uniform coalesced
// global loads from fragment-ordered wf. A frags: direct global float4 loads,
// hi/lo split in registers. No LDS, no barriers.
// ---------------------------------------------------------------------------
template <int K, int NCOL, bool ELU_IN, bool LRELU, bool BIAS>
__global__ __launch_bounds__(256) void mfma_gemm_kernel(
    const float* __restrict__ X, const unsigned short* __restrict__ wf,
    const float* __restrict__ bias, float* __restrict__ Y, int nrows)
{
    constexpr int NF = NCOL / 16;
    constexpr int NK = K / 32;

    const int t = threadIdx.x;
    const int lane = t & 63;
    const int w = t >> 6;
    const int row0 = blockIdx.x * 64 + w * 16;

    const int arow = row0 + (lane & 15);
    const bool rowok = arow < nrows;
    const float* xrow = X + (size_t)arow * K + ((lane >> 4) * 8);

    f32x4 acc[NF];
#pragma unroll
    for (int c = 0; c < NF; ++c) acc[c] = (f32x4){0.f, 0.f, 0.f, 0.f};

#pragma unroll 2
    for (int kk = 0; kk < NK; ++kk) {
        // A fragment: 8 fp32 -> hi/lo bf16 in regs
        float4 v0 = make_float4(0.f, 0.f, 0.f, 0.f);
        float4 v1 = v0;
        if (rowok) {
            v0 = *(const float4*)&xrow[kk * 32];
            v1 = *(const float4*)&xrow[kk * 32 + 4];
        }
        if (ELU_IN) {
            v0.x = (v0.x > 0.f) ? v0.x : expm1f(v0.x);
            v0.y = (v0.y > 0.f) ? v0.y : expm1f(v0.y);
            v0.z = (v0.z > 0.f) ? v0.z : expm1f(v0.z);
            v0.w = (v0.w > 0.f) ? v0.w : expm1f(v0.w);
            v1.x = (v1.x > 0.f) ? v1.x : expm1f(v1.x);
            v1.y = (v1.y > 0.f) ? v1.y : expm1f(v1.y);
            v1.z = (v1.z > 0.f) ? v1.z : expm1f(v1.z);
            v1.w = (v1.w > 0.f) ? v1.w : expm1f(v1.w);
        }
        float a[8] = {v0.x, v0.y, v0.z, v0.w, v1.x, v1.y, v1.z, v1.w};
        short8v ah, al;
#pragma unroll
        for (int j = 0; j < 8; ++j) {
            unsigned short hb = f2bf_rne(a[j]);
            ah[j] = (short)hb;
            al[j] = (short)f2bf_rne(a[j] - bf2f(hb));
        }
        // B fragments: wave-uniform coalesced loads
        const unsigned short* wfk = wf + (size_t)(kk * NF * 2) * 512 + lane * 8;
        short8v bh[NF], bl[NF];
#pragma unroll
        for (int c = 0; c < NF; ++c) {
            bh[c] = *(const short8v*)(wfk + (c * 2 + 0) * 512);
            bl[c] = *(const short8v*)(wfk + (c * 2 + 1) * 512);
        }
#pragma unroll
        for (int c = 0; c < NF; ++c) {
            acc[c] = __builtin_amdgcn_mfma_f32_16x16x32_bf16(ah, bh[c], acc[c], 0, 0, 0);
            acc[c] = __builtin_amdgcn_mfma_f32_16x16x32_bf16(al, bh[c], acc[c], 0, 0, 0);
            acc[c] = __builtin_amdgcn_mfma_f32_16x16x32_bf16(ah, bl[c], acc[c], 0, 0, 0);
        }
    }

    // epilogue: C/D layout col=lane&15, row=(lane>>4)*4+q
#pragma unroll
    for (int c = 0; c < NF; ++c) {
        int gcol = c * 16 + (lane & 15);
        float bv = BIAS ? bias[gcol] : 0.f;
#pragma unroll
        for (int q = 0; q < 4; ++q) {
            int grow = row0 + (lane >> 4) * 4 + q;
            if (grow < nrows) {
                float o = acc[c][q] + bv;
                if (LRELU) o = (o > 0.f) ? o : 0.01f * o;
                Y[(size_t)grow * NCOL + gcol] = o;
            }
        }
    }
}

// ---------------------------------------------------------------------------
// Gather: out[d,:] = dis[d]*(h[d]*dis[d] + sum h[s]*dis[s])
// 32 lanes per node, float4/lane (128 floats/row); 8 nodes per 256-block.
// ---------------------------------------------------------------------------
__global__ __launch_bounds__(256) void gather_kernel(const float* __restrict__ h,
                                                     const int* __restrict__ row_ptr,
                                                     const int* __restrict__ csr,
                                                     const float* __restrict__ dis,
                                                     float* __restrict__ outp, int n) {
    int node = blockIdx.x * 8 + (threadIdx.x >> 5);
    int l = threadIdx.x & 31;
    if (node >= n) return;
    int beg = (node == 0) ? 0 : row_ptr[node - 1];
    int end = row_ptr[node];
    float dd = dis[node];
    const float4* h4 = (const float4*)h;
    float4 self = h4[(size_t)node * 32 + l];
    float ax = self.x * dd, ay = self.y * dd, az = self.z * dd, aw = self.w * dd;
    int j = beg;
    for (; j + 4 <= end; j += 4) {
        int s0 = csr[j + 0], s1 = csr[j + 1], s2 = csr[j + 2], s3 = csr[j + 3];
        float d0 = dis[s0], d1 = dis[s1], d2 = dis[s2], d3 = dis[s3];
        float4 v0 = h4[(size_t)s0 * 32 + l];
        float4 v1 = h4[(size_t)s1 * 32 + l];
        float4 v2 = h4[(size_t)s2 * 32 + l];
        float4 v3 = h4[(size_t)s3 * 32 + l];
        ax += v0.x * d0 + v1.x * d1 + v2.x * d2 + v3.x * d3;
        ay += v0.y * d0 + v1.y * d1 + v2.y * d2 + v3.y * d3;
        az += v0.z * d0 + v1.z * d1 + v2.z * d2 + v3.z * d3;
        aw += v0.w * d0 + v1.w * d1 + v2.w * d2 + v3.w * d3;
    }
    for (; j < end; ++j) {
        int s = csr[j];
        float ds = dis[s];
        float4 v = h4[(size_t)s * 32 + l];
        ax += v.x * ds; ay += v.y * ds; az += v.z * ds; aw += v.w * ds;
    }
    float4 o;
    o.x = ax * dd; o.y = ay * dd; o.z = az * dd; o.w = aw * dd;
    ((float4*)outp)[(size_t)node * 32 + l] = o;
}

// ---------------------------------------------------------------------------
// decoder: Z layout [node][64] = [tf2(32) | tg2(32)]; 8 lanes per sample
// ---------------------------------------------------------------------------
__global__ void dot_kernel(const float* __restrict__ Z,
                           const int* __restrict__ ts, float* __restrict__ out, int m) {
    int gid = blockIdx.x * 256 + threadIdx.x;
    int s = gid >> 3;
    int l = gid & 7;
    if (s >= m) return;
    int ti = ts[2 * s + 0];
    int ui = ts[2 * s + 1];
    float4 a = *(const float4*)&Z[(size_t)ti * 64 + l * 4];
    float4 b = *(const float4*)&Z[(size_t)ui * 64 + 32 + l * 4];
    float d = a.x * b.x + a.y * b.y + a.z * b.z + a.w * b.w;
    d += __shfl_down(d, 4, 8);
    d += __shfl_down(d, 2, 8);
    d += __shfl_down(d, 1, 8);
    if (l == 0) out[s] = d;
}

// ---------------------------------------------------------------------------
extern "C" void kernel_launch(void* const* d_in, const int* in_sizes, int n_in,
                              void* d_out, int out_size, void* d_ws, size_t ws_size,
                              hipStream_t stream) {
    const float* x     = (const float*)d_in[0];
    const int*   ei    = (const int*)d_in[1];
    const int*   ts    = (const int*)d_in[2];
    const float* W1    = (const float*)d_in[3];
    const float* W2    = (const float*)d_in[4];
    const float* tf_w1 = (const float*)d_in[5];
    const float* tf_b1 = (const float*)d_in[6];
    const float* tf_w2 = (const float*)d_in[7];
    const float* tf_b2 = (const float*)d_in[8];
    const float* tg_w1 = (const float*)d_in[9];
    const float* tg_b1 = (const float*)d_in[10];
    const float* tg_w2 = (const float*)d_in[11];
    const float* tg_b2 = (const float*)d_in[12];
    float* out = (float*)d_out;

    const int n = in_sizes[0] / 256;   // 50000
    const int e = in_sizes[1] / 2;     // 640000
    const int m = in_sizes[2] / 2;     // 400000
    const int* src = ei;
    const int* dstp = ei + e;

    // workspace layout (float units):
    //   dis[50176] | row_ptr[50176] | ideg/csr[640064] |
    //   wfrag[73728] (147456 shorts: W1f|W2f|H1f|H2f) | bcat1[128] bcat2[64] | A | B | C
    float* wsf = (float*)d_ws;
    float* dis     = wsf;
    int*   row_ptr = (int*)(wsf + 50176);
    int*   ideg    = (int*)(wsf + 100352);
    int*   csr     = (int*)(wsf + 100352);
    unsigned short* wfrag = (unsigned short*)(wsf + 740416);
    unsigned short* w1f = wfrag;
    unsigned short* w2f = wfrag + 65536;
    unsigned short* h1f = wfrag + 98304;
    unsigned short* h2f = wfrag + 131072;
    float* bcat1 = wsf + 740416 + 73728;   // 814144
    float* bcat2 = wsf + 814272;
    float* A = wsf + 814336;
    float* B = A + (size_t)n * 128;
    float* C = B + (size_t)n * 128;

    const int nb_n = (n + 255) / 256;
    const int nb_e = (e + 255) / 256;
    const int gg   = (n + 7) / 8;      // gather grid (8 nodes/block)
    const int gm   = (n + 63) / 64;    // MFMA grid: 782

    // 1) CSR build + normalization
    zero_ideg_kernel<<<nb_n, 256, 0, stream>>>(ideg, n);
    ideg_accum_kernel<<<nb_e, 256, 0, stream>>>(ideg, dstp, e);
    scan_kernel<<<1, 1024, 0, stream>>>(ideg, row_ptr, dis, n);
    fill_kernel<<<nb_e, 256, 0, stream>>>(src, dstp, row_ptr, csr, e);

    // 1b) weight prep (fragment order) + biases
    prep_weights_kernel<<<(147648 + 255) / 256, 256, 0, stream>>>(
        W1, W2, tf_w1, tf_b1, tf_w2, tf_b2, tg_w1, tg_b1, tg_w2, tg_b2,
        wfrag, bcat1, bcat2);

    // 2) layer 1: A = x@W1 ; B = gather(A)
    mfma_gemm_kernel<256, 128, false, false, false><<<gm, 256, 0, stream>>>(x, w1f, nullptr, A, n);
    gather_kernel<<<gg, 256, 0, stream>>>(A, row_ptr, csr, dis, B, n);

    // 3) layer 2: C = elu(B)@W2 ; A = gather(C)  (A = embed)
    mfma_gemm_kernel<128, 128, true, false, false><<<gm, 256, 0, stream>>>(B, w2f, nullptr, C, n);
    gather_kernel<<<gg, 256, 0, stream>>>(C, row_ptr, csr, dis, A, n);

    // 4) heads: B = lrelu(A@[tf_w1|tg_w1]+bcat1) ; C = lrelu(B@blockdiag+bcat2)
    mfma_gemm_kernel<128, 128, false, true, true><<<gm, 256, 0, stream>>>(A, h1f, bcat1, B, n);
    mfma_gemm_kernel<128, 64, false, true, true><<<gm, 256, 0, stream>>>(B, h2f, bcat2, C, n);

    // 5) decoder
    dot_kernel<<<(m * 8 + 255) / 256, 256, 0, stream>>>(C, ts, out, m);
}

// Round 8
// 363.475 us; speedup vs baseline: 6.0699x; 1.1141x over previous
//
#include <hip/hip_runtime.h>
#include <hip/hip_bf16.h>
#include <math.h>

// Problem constants: N=50000, E=640000, M=400000
// D_IN=256, H1=128, H2=128, H3=64, D_OUT=32
//
// Round 8: replace the single-block serial scan (56.6us, occupancy 0.17%)
// with a 3-kernel parallel scan (block-local scan -> 1-wave partials scan
// -> add offsets). Everything else unchanged from round 7.

typedef __attribute__((ext_vector_type(8))) short short8v;   // 8 bf16 (4 VGPR)
typedef __attribute__((ext_vector_type(4))) float f32x4;     // MFMA acc

__device__ inline unsigned short f2bf_rne(float f) {
    unsigned u = __float_as_uint(f);
    unsigned r = u + 0x7FFFu + ((u >> 16) & 1u);
    return (unsigned short)(r >> 16);
}
__device__ inline float bf2f(unsigned short h) {
    return __uint_as_float(((unsigned)h) << 16);
}

// ---------------------------------------------------------------------------
// CSR build + norm
// ---------------------------------------------------------------------------
__global__ void zero_ideg_kernel(int* __restrict__ ideg, int n) {
    int i = blockIdx.x * 256 + threadIdx.x;
    if (i < n) ideg[i] = 0;
}

__global__ void ideg_accum_kernel(int* __restrict__ ideg, const int* __restrict__ dst, int e) {
    int i = blockIdx.x * 256 + threadIdx.x;
    if (i < e) atomicAdd(&ideg[dst[i]], 1);
}

// Parallel scan stage 1: 1024 elems/block (4/thread, int4). Writes block-local
// exclusive scan to row_ptr, block total to partials[b], dis = rsqrt(1+deg).
__global__ __launch_bounds__(256) void scan_blk_kernel(const int* __restrict__ ideg,
                                                       int* __restrict__ row_ptr,
                                                       float* __restrict__ dis,
                                                       int* __restrict__ partials, int n) {
    __shared__ int wsum[4];
    const int t = threadIdx.x;
    const int lane = t & 63;
    const int wid = t >> 6;
    const int i0 = blockIdx.x * 1024 + t * 4;
    int4 v = make_int4(0, 0, 0, 0);
    if (i0 + 3 < n) {
        v = *(const int4*)&ideg[i0];
    } else if (i0 < n) {
        v.x = ideg[i0];
        if (i0 + 1 < n) v.y = ideg[i0 + 1];
        if (i0 + 2 < n) v.z = ideg[i0 + 2];
    }
    if (i0 < n) {
        dis[i0] = rsqrtf(1.f + (float)v.x);
        if (i0 + 1 < n) dis[i0 + 1] = rsqrtf(1.f + (float)v.y);
        if (i0 + 2 < n) dis[i0 + 2] = rsqrtf(1.f + (float)v.z);
        if (i0 + 3 < n) dis[i0 + 3] = rsqrtf(1.f + (float)v.w);
    }
    int s = v.x + v.y + v.z + v.w;
    int incl = s;
#pragma unroll
    for (int off = 1; off < 64; off <<= 1) {
        int tv = __shfl_up(incl, off, 64);
        if (lane >= off) incl += tv;
    }
    if (lane == 63) wsum[wid] = incl;
    __syncthreads();
    if (t == 0) {
        int a = 0;
#pragma unroll
        for (int ww = 0; ww < 4; ++ww) { int tmp = wsum[ww]; wsum[ww] = a; a += tmp; }
    }
    __syncthreads();
    int ex = wsum[wid] + incl - s;
    if (i0 < n) {
        row_ptr[i0] = ex;
        if (i0 + 1 < n) row_ptr[i0 + 1] = ex + v.x;
        if (i0 + 2 < n) row_ptr[i0 + 2] = ex + v.x + v.y;
        if (i0 + 3 < n) row_ptr[i0 + 3] = ex + v.x + v.y + v.z;
    }
    if (t == 255) partials[blockIdx.x] = wsum[3] + incl;
}

// Parallel scan stage 2: exclusive scan of block totals (nb<=64, one wave).
__global__ void scan_part_kernel(int* __restrict__ partials, int nb) {
    int lane = threadIdx.x;
    int v = (lane < nb) ? partials[lane] : 0;
    int incl = v;
#pragma unroll
    for (int off = 1; off < 64; off <<= 1) {
        int tv = __shfl_up(incl, off, 64);
        if (lane >= off) incl += tv;
    }
    if (lane < nb) partials[lane] = incl - v;
}

// Parallel scan stage 3: add block offsets.
__global__ void scan_add_kernel(int* __restrict__ row_ptr, const int* __restrict__ partials, int n) {
    int i = blockIdx.x * 256 + threadIdx.x;
    if (i < n) row_ptr[i] += partials[i >> 10];
}

__global__ void fill_kernel(const int* __restrict__ src, const int* __restrict__ dst,
                            int* __restrict__ row_ptr, int* __restrict__ csr, int e) {
    int i = blockIdx.x * 256 + threadIdx.x;
    if (i < e) {
        int d = dst[i];
        int pos = atomicAdd(&row_ptr[d], 1);
        csr[pos] = src[i];
    }
}

// ---------------------------------------------------------------------------
// Weight prep in MFMA-fragment order (unchanged).
// Fragment layout (shorts): id = ((kk*NF + c)*2 + h)*512 + lane*8 + j
//   k = kk*32 + (lane>>4)*8 + j ; col = c*16 + (lane&15) ; h: 0=hi 1=lo
// Ranges (shorts): W1f 65536 | W2f 32768 | H1f 32768 | H2f 16384 = 147456
// ---------------------------------------------------------------------------
__global__ void prep_weights_kernel(
    const float* __restrict__ W1, const float* __restrict__ W2,
    const float* __restrict__ tfw1, const float* __restrict__ tfb1,
    const float* __restrict__ tfw2, const float* __restrict__ tfb2,
    const float* __restrict__ tgw1, const float* __restrict__ tgb1,
    const float* __restrict__ tgw2, const float* __restrict__ tgb2,
    unsigned short* __restrict__ wf,
    float* __restrict__ bcat1, float* __restrict__ bcat2)
{
    int id = blockIdx.x * 256 + threadIdx.x;
    if (id >= 147456) {
        if (id < 147456 + 128) {
            int c = id - 147456;
            bcat1[c] = (c < 64) ? tfb1[c] : tgb1[c - 64];
        } else if (id < 147456 + 192) {
            int c = id - 147456 - 128;
            bcat2[c] = (c < 32) ? tfb2[c] : tgb2[c - 32];
        }
        return;
    }
    int base, NF;
    int lid;
    if (id < 65536)       { base = 0;      NF = 8; lid = id; }
    else if (id < 98304)  { base = 65536;  NF = 8; lid = id - 65536; }
    else if (id < 131072) { base = 98304;  NF = 8; lid = id - 98304; }
    else                  { base = 131072; NF = 4; lid = id - 131072; }

    int j    = lid & 7;
    int lane = (lid >> 3) & 63;
    int h    = (lid >> 9) & 1;
    int rest = lid >> 10;
    int c    = rest % NF;
    int kk   = rest / NF;
    int k    = kk * 32 + (lane >> 4) * 8 + j;
    int col  = c * 16 + (lane & 15);

    float w;
    if (id < 65536) {                 // W1: [256][128]
        w = W1[k * 128 + col];
    } else if (id < 98304) {          // W2: [128][128]
        w = W2[k * 128 + col];
    } else if (id < 131072) {         // H1 cat: [128][128] = [tf_w1 | tg_w1]
        w = (col < 64) ? tfw1[k * 64 + col] : tgw1[k * 64 + (col - 64)];
    } else {                          // H2 block-diag: [128][64]
        w = 0.f;
        if (k < 64 && col < 32) w = tfw2[k * 32 + col];
        else if (k >= 64 && col >= 32) w = tgw2[(k - 64) * 32 + (col - 32)];
    }
    unsigned short hb = f2bf_rne(w);
    wf[base + lid] = h ? f2bf_rne(w - bf2f(hb)) : hb;
}

// ---------------------------------------------------------------------------
// LDS-free MFMA GEMM (unchanged from round 7).
// ---------------------------------------------------------------------------
template <int K, int NCOL, bool ELU_IN, bool LRELU, bool BIAS>
__global__ __launch_bounds__(256) void mfma_gemm_kernel(
    const float* __restrict__ X, const unsigned short* __restrict__ wf,
    const float* __restrict__ bias, float* __restrict__ Y, int nrows)
{
    constexpr int NF = NCOL / 16;
    constexpr int NK = K / 32;

    const int t = threadIdx.x;
    const int lane = t & 63;
    const int w = t >> 6;
    const int row0 = blockIdx.x * 64 + w * 16;

    const int arow = row0 + (lane & 15);
    const bool rowok = arow < nrows;
    const float* xrow = X + (size_t)arow * K + ((lane >> 4) * 8);

    f32x4 acc[NF];
#pragma unroll
    for (int c = 0; c < NF; ++c) acc[c] = (f32x4){0.f, 0.f, 0.f, 0.f};

#pragma unroll 2
    for (int kk = 0; kk < NK; ++kk) {
        float4 v0 = make_float4(0.f, 0.f, 0.f, 0.f);
        float4 v1 = v0;
        if (rowok) {
            v0 = *(const float4*)&xrow[kk * 32];
            v1 = *(const float4*)&xrow[kk * 32 + 4];
        }
        if (ELU_IN) {
            v0.x = (v0.x > 0.f) ? v0.x : expm1f(v0.x);
            v0.y = (v0.y > 0.f) ? v0.y : expm1f(v0.y);
            v0.z = (v0.z > 0.f) ? v0.z : expm1f(v0.z);
            v0.w = (v0.w > 0.f) ? v0.w : expm1f(v0.w);
            v1.x = (v1.x > 0.f) ? v1.x : expm1f(v1.x);
            v1.y = (v1.y > 0.f) ? v1.y : expm1f(v1.y);
            v1.z = (v1.z > 0.f) ? v1.z : expm1f(v1.z);
            v1.w = (v1.w > 0.f) ? v1.w : expm1f(v1.w);
        }
        float a[8] = {v0.x, v0.y, v0.z, v0.w, v1.x, v1.y, v1.z, v1.w};
        short8v ah, al;
#pragma unroll
        for (int j = 0; j < 8; ++j) {
            unsigned short hb = f2bf_rne(a[j]);
            ah[j] = (short)hb;
            al[j] = (short)f2bf_rne(a[j] - bf2f(hb));
        }
        const unsigned short* wfk = wf + (size_t)(kk * NF * 2) * 512 + lane * 8;
        short8v bh[NF], bl[NF];
#pragma unroll
        for (int c = 0; c < NF; ++c) {
            bh[c] = *(const short8v*)(wfk + (c * 2 + 0) * 512);
            bl[c] = *(const short8v*)(wfk + (c * 2 + 1) * 512);
        }
#pragma unroll
        for (int c = 0; c < NF; ++c) {
            acc[c] = __builtin_amdgcn_mfma_f32_16x16x32_bf16(ah, bh[c], acc[c], 0, 0, 0);
            acc[c] = __builtin_amdgcn_mfma_f32_16x16x32_bf16(al, bh[c], acc[c], 0, 0, 0);
            acc[c] = __builtin_amdgcn_mfma_f32_16x16x32_bf16(ah, bl[c], acc[c], 0, 0, 0);
        }
    }

#pragma unroll
    for (int c = 0; c < NF; ++c) {
        int gcol = c * 16 + (lane & 15);
        float bv = BIAS ? bias[gcol] : 0.f;
#pragma unroll
        for (int q = 0; q < 4; ++q) {
            int grow = row0 + (lane >> 4) * 4 + q;
            if (grow < nrows) {
                float o = acc[c][q] + bv;
                if (LRELU) o = (o > 0.f) ? o : 0.01f * o;
                Y[(size_t)grow * NCOL + gcol] = o;
            }
        }
    }
}

// ---------------------------------------------------------------------------
// Gather (unchanged): 32 lanes/node, float4/lane, 8 nodes per 256-block.
// ---------------------------------------------------------------------------
__global__ __launch_bounds__(256) void gather_kernel(const float* __restrict__ h,
                                                     const int* __restrict__ row_ptr,
                                                     const int* __restrict__ csr,
                                                     const float* __restrict__ dis,
                                                     float* __restrict__ outp, int n) {
    int node = blockIdx.x * 8 + (threadIdx.x >> 5);
    int l = threadIdx.x & 31;
    if (node >= n) return;
    int beg = (node == 0) ? 0 : row_ptr[node - 1];
    int end = row_ptr[node];
    float dd = dis[node];
    const float4* h4 = (const float4*)h;
    float4 self = h4[(size_t)node * 32 + l];
    float ax = self.x * dd, ay = self.y * dd, az = self.z * dd, aw = self.w * dd;
    int j = beg;
    for (; j + 4 <= end; j += 4) {
        int s0 = csr[j + 0], s1 = csr[j + 1], s2 = csr[j + 2], s3 = csr[j + 3];
        float d0 = dis[s0], d1 = dis[s1], d2 = dis[s2], d3 = dis[s3];
        float4 v0 = h4[(size_t)s0 * 32 + l];
        float4 v1 = h4[(size_t)s1 * 32 + l];
        float4 v2 = h4[(size_t)s2 * 32 + l];
        float4 v3 = h4[(size_t)s3 * 32 + l];
        ax += v0.x * d0 + v1.x * d1 + v2.x * d2 + v3.x * d3;
        ay += v0.y * d0 + v1.y * d1 + v2.y * d2 + v3.y * d3;
        az += v0.z * d0 + v1.z * d1 + v2.z * d2 + v3.z * d3;
        aw += v0.w * d0 + v1.w * d1 + v2.w * d2 + v3.w * d3;
    }
    for (; j < end; ++j) {
        int s = csr[j];
        float ds = dis[s];
        float4 v = h4[(size_t)s * 32 + l];
        ax += v.x * ds; ay += v.y * ds; az += v.z * ds; aw += v.w * ds;
    }
    float4 o;
    o.x = ax * dd; o.y = ay * dd; o.z = az * dd; o.w = aw * dd;
    ((float4*)outp)[(size_t)node * 32 + l] = o;
}

// ---------------------------------------------------------------------------
// decoder (unchanged): Z layout [node][64] = [tf2(32) | tg2(32)]
// ---------------------------------------------------------------------------
__global__ void dot_kernel(const float* __restrict__ Z,
                           const int* __restrict__ ts, float* __restrict__ out, int m) {
    int gid = blockIdx.x * 256 + threadIdx.x;
    int s = gid >> 3;
    int l = gid & 7;
    if (s >= m) return;
    int ti = ts[2 * s + 0];
    int ui = ts[2 * s + 1];
    float4 a = *(const float4*)&Z[(size_t)ti * 64 + l * 4];
    float4 b = *(const float4*)&Z[(size_t)ui * 64 + 32 + l * 4];
    float d = a.x * b.x + a.y * b.y + a.z * b.z + a.w * b.w;
    d += __shfl_down(d, 4, 8);
    d += __shfl_down(d, 2, 8);
    d += __shfl_down(d, 1, 8);
    if (l == 0) out[s] = d;
}

// ---------------------------------------------------------------------------
extern "C" void kernel_launch(void* const* d_in, const int* in_sizes, int n_in,
                              void* d_out, int out_size, void* d_ws, size_t ws_size,
                              hipStream_t stream) {
    const float* x     = (const float*)d_in[0];
    const int*   ei    = (const int*)d_in[1];
    const int*   ts    = (const int*)d_in[2];
    const float* W1    = (const float*)d_in[3];
    const float* W2    = (const float*)d_in[4];
    const float* tf_w1 = (const float*)d_in[5];
    const float* tf_b1 = (const float*)d_in[6];
    const float* tf_w2 = (const float*)d_in[7];
    const float* tf_b2 = (const float*)d_in[8];
    const float* tg_w1 = (const float*)d_in[9];
    const float* tg_b1 = (const float*)d_in[10];
    const float* tg_w2 = (const float*)d_in[11];
    const float* tg_b2 = (const float*)d_in[12];
    float* out = (float*)d_out;

    const int n = in_sizes[0] / 256;   // 50000
    const int e = in_sizes[1] / 2;     // 640000
    const int m = in_sizes[2] / 2;     // 400000
    const int* src = ei;
    const int* dstp = ei + e;

    // workspace layout (float units):
    //   dis[50176] | row_ptr[50176] (partials at +50048) | ideg/csr[640064] |
    //   wfrag[73728] (147456 shorts) | bcat1[128] bcat2[64] | A | B | C
    float* wsf = (float*)d_ws;
    float* dis     = wsf;
    int*   row_ptr = (int*)(wsf + 50176);
    int*   partials = row_ptr + 50048;          // 128 spare ints in row_ptr region
    int*   ideg    = (int*)(wsf + 100352);
    int*   csr     = (int*)(wsf + 100352);
    unsigned short* wfrag = (unsigned short*)(wsf + 740416);
    unsigned short* w1f = wfrag;
    unsigned short* w2f = wfrag + 65536;
    unsigned short* h1f = wfrag + 98304;
    unsigned short* h2f = wfrag + 131072;
    float* bcat1 = wsf + 740416 + 73728;
    float* bcat2 = wsf + 814272;
    float* A = wsf + 814336;
    float* B = A + (size_t)n * 128;
    float* C = B + (size_t)n * 128;

    const int nb_n = (n + 255) / 256;
    const int nb_e = (e + 255) / 256;
    const int nsb  = (n + 1023) / 1024;  // scan blocks: 49
    const int gg   = (n + 7) / 8;        // gather grid (8 nodes/block)
    const int gm   = (n + 63) / 64;      // MFMA grid: 782

    // 1) CSR build + normalization (parallel scan)
    zero_ideg_kernel<<<nb_n, 256, 0, stream>>>(ideg, n);
    ideg_accum_kernel<<<nb_e, 256, 0, stream>>>(ideg, dstp, e);
    scan_blk_kernel<<<nsb, 256, 0, stream>>>(ideg, row_ptr, dis, partials, n);
    scan_part_kernel<<<1, 64, 0, stream>>>(partials, nsb);
    scan_add_kernel<<<nb_n, 256, 0, stream>>>(row_ptr, partials, n);
    fill_kernel<<<nb_e, 256, 0, stream>>>(src, dstp, row_ptr, csr, e);

    // 1b) weight prep (fragment order) + biases
    prep_weights_kernel<<<(147648 + 255) / 256, 256, 0, stream>>>(
        W1, W2, tf_w1, tf_b1, tf_w2, tf_b2, tg_w1, tg_b1, tg_w2, tg_b2,
        wfrag, bcat1, bcat2);

    // 2) layer 1: A = x@W1 ; B = gather(A)
    mfma_gemm_kernel<256, 128, false, false, false><<<gm, 256, 0, stream>>>(x, w1f, nullptr, A, n);
    gather_kernel<<<gg, 256, 0, stream>>>(A, row_ptr, csr, dis, B, n);

    // 3) layer 2: C = elu(B)@W2 ; A = gather(C)  (A = embed)
    mfma_gemm_kernel<128, 128, true, false, false><<<gm, 256, 0, stream>>>(B, w2f, nullptr, C, n);
    gather_kernel<<<gg, 256, 0, stream>>>(C, row_ptr, csr, dis, A, n);

    // 4) heads: B = lrelu(A@[tf_w1|tg_w1]+bcat1) ; C = lrelu(B@blockdiag+bcat2)
    mfma_gemm_kernel<128, 128, false, true, true><<<gm, 256, 0, stream>>>(A, h1f, bcat1, B, n);
    mfma_gemm_kernel<128, 64, false, true, true><<<gm, 256, 0, stream>>>(B, h2f, bcat2, C, n);

    // 5) decoder
    dot_kernel<<<(m * 8 + 255) / 256, 256, 0, stream>>>(C, ts, out, m);
}

// Round 9
// 354.426 us; speedup vs baseline: 6.2249x; 1.0255x over previous
//
#include <hip/hip_runtime.h>
#include <hip/hip_bf16.h>
#include <math.h>

// Problem constants: N=50000, E=640000, M=400000
// D_IN=256, H1=128, H2=128, H3=64, D_OUT=32
//
// Round 9:
//  (a) gather: index-broadcast restructure — 32 edge indices + dis loaded in
//      one coalesced round trip, shfl-broadcast; h-row loads all independent.
//  (b) heads fused into one kernel: stage-1 MFMA -> in-register bf16 hi/lo ->
//      per-wave LDS ([16][136] pad) -> stage-2 MFMA. No B round trip.
// Everything else unchanged from round 8.

typedef __attribute__((ext_vector_type(8))) short short8v;   // 8 bf16 (4 VGPR)
typedef __attribute__((ext_vector_type(4))) float f32x4;     // MFMA acc

__device__ inline unsigned short f2bf_rne(float f) {
    unsigned u = __float_as_uint(f);
    unsigned r = u + 0x7FFFu + ((u >> 16) & 1u);
    return (unsigned short)(r >> 16);
}
__device__ inline float bf2f(unsigned short h) {
    return __uint_as_float(((unsigned)h) << 16);
}

// ---------------------------------------------------------------------------
// CSR build + norm
// ---------------------------------------------------------------------------
__global__ void zero_ideg_kernel(int* __restrict__ ideg, int n) {
    int i = blockIdx.x * 256 + threadIdx.x;
    if (i < n) ideg[i] = 0;
}

__global__ void ideg_accum_kernel(int* __restrict__ ideg, const int* __restrict__ dst, int e) {
    int i = blockIdx.x * 256 + threadIdx.x;
    if (i < e) atomicAdd(&ideg[dst[i]], 1);
}

__global__ __launch_bounds__(256) void scan_blk_kernel(const int* __restrict__ ideg,
                                                       int* __restrict__ row_ptr,
                                                       float* __restrict__ dis,
                                                       int* __restrict__ partials, int n) {
    __shared__ int wsum[4];
    const int t = threadIdx.x;
    const int lane = t & 63;
    const int wid = t >> 6;
    const int i0 = blockIdx.x * 1024 + t * 4;
    int4 v = make_int4(0, 0, 0, 0);
    if (i0 + 3 < n) {
        v = *(const int4*)&ideg[i0];
    } else if (i0 < n) {
        v.x = ideg[i0];
        if (i0 + 1 < n) v.y = ideg[i0 + 1];
        if (i0 + 2 < n) v.z = ideg[i0 + 2];
    }
    if (i0 < n) {
        dis[i0] = rsqrtf(1.f + (float)v.x);
        if (i0 + 1 < n) dis[i0 + 1] = rsqrtf(1.f + (float)v.y);
        if (i0 + 2 < n) dis[i0 + 2] = rsqrtf(1.f + (float)v.z);
        if (i0 + 3 < n) dis[i0 + 3] = rsqrtf(1.f + (float)v.w);
    }
    int s = v.x + v.y + v.z + v.w;
    int incl = s;
#pragma unroll
    for (int off = 1; off < 64; off <<= 1) {
        int tv = __shfl_up(incl, off, 64);
        if (lane >= off) incl += tv;
    }
    if (lane == 63) wsum[wid] = incl;
    __syncthreads();
    if (t == 0) {
        int a = 0;
#pragma unroll
        for (int ww = 0; ww < 4; ++ww) { int tmp = wsum[ww]; wsum[ww] = a; a += tmp; }
    }
    __syncthreads();
    int ex = wsum[wid] + incl - s;
    if (i0 < n) {
        row_ptr[i0] = ex;
        if (i0 + 1 < n) row_ptr[i0 + 1] = ex + v.x;
        if (i0 + 2 < n) row_ptr[i0 + 2] = ex + v.x + v.y;
        if (i0 + 3 < n) row_ptr[i0 + 3] = ex + v.x + v.y + v.z;
    }
    if (t == 255) partials[blockIdx.x] = wsum[3] + incl;
}

__global__ void scan_part_kernel(int* __restrict__ partials, int nb) {
    int lane = threadIdx.x;
    int v = (lane < nb) ? partials[lane] : 0;
    int incl = v;
#pragma unroll
    for (int off = 1; off < 64; off <<= 1) {
        int tv = __shfl_up(incl, off, 64);
        if (lane >= off) incl += tv;
    }
    if (lane < nb) partials[lane] = incl - v;
}

__global__ void scan_add_kernel(int* __restrict__ row_ptr, const int* __restrict__ partials, int n) {
    int i = blockIdx.x * 256 + threadIdx.x;
    if (i < n) row_ptr[i] += partials[i >> 10];
}

__global__ void fill_kernel(const int* __restrict__ src, const int* __restrict__ dst,
                            int* __restrict__ row_ptr, int* __restrict__ csr, int e) {
    int i = blockIdx.x * 256 + threadIdx.x;
    if (i < e) {
        int d = dst[i];
        int pos = atomicAdd(&row_ptr[d], 1);
        csr[pos] = src[i];
    }
}

// ---------------------------------------------------------------------------
// Weight prep in MFMA-fragment order (unchanged).
// ---------------------------------------------------------------------------
__global__ void prep_weights_kernel(
    const float* __restrict__ W1, const float* __restrict__ W2,
    const float* __restrict__ tfw1, const float* __restrict__ tfb1,
    const float* __restrict__ tfw2, const float* __restrict__ tfb2,
    const float* __restrict__ tgw1, const float* __restrict__ tgb1,
    const float* __restrict__ tgw2, const float* __restrict__ tgb2,
    unsigned short* __restrict__ wf,
    float* __restrict__ bcat1, float* __restrict__ bcat2)
{
    int id = blockIdx.x * 256 + threadIdx.x;
    if (id >= 147456) {
        if (id < 147456 + 128) {
            int c = id - 147456;
            bcat1[c] = (c < 64) ? tfb1[c] : tgb1[c - 64];
        } else if (id < 147456 + 192) {
            int c = id - 147456 - 128;
            bcat2[c] = (c < 32) ? tfb2[c] : tgb2[c - 32];
        }
        return;
    }
    int base, NF;
    int lid;
    if (id < 65536)       { base = 0;      NF = 8; lid = id; }
    else if (id < 98304)  { base = 65536;  NF = 8; lid = id - 65536; }
    else if (id < 131072) { base = 98304;  NF = 8; lid = id - 98304; }
    else                  { base = 131072; NF = 4; lid = id - 131072; }

    int j    = lid & 7;
    int lane = (lid >> 3) & 63;
    int h    = (lid >> 9) & 1;
    int rest = lid >> 10;
    int c    = rest % NF;
    int kk   = rest / NF;
    int k    = kk * 32 + (lane >> 4) * 8 + j;
    int col  = c * 16 + (lane & 15);

    float w;
    if (id < 65536) {                 // W1: [256][128]
        w = W1[k * 128 + col];
    } else if (id < 98304) {          // W2: [128][128]
        w = W2[k * 128 + col];
    } else if (id < 131072) {         // H1 cat: [128][128] = [tf_w1 | tg_w1]
        w = (col < 64) ? tfw1[k * 64 + col] : tgw1[k * 64 + (col - 64)];
    } else {                          // H2 block-diag: [128][64]
        w = 0.f;
        if (k < 64 && col < 32) w = tfw2[k * 32 + col];
        else if (k >= 64 && col >= 32) w = tgw2[(k - 64) * 32 + (col - 32)];
    }
    unsigned short hb = f2bf_rne(w);
    wf[base + lid] = h ? f2bf_rne(w - bf2f(hb)) : hb;
}

// ---------------------------------------------------------------------------
// LDS-free MFMA GEMM (unchanged from round 7/8) — used for the two GCN layers.
// ---------------------------------------------------------------------------
template <int K, int NCOL, bool ELU_IN, bool LRELU, bool BIAS>
__global__ __launch_bounds__(256) void mfma_gemm_kernel(
    const float* __restrict__ X, const unsigned short* __restrict__ wf,
    const float* __restrict__ bias, float* __restrict__ Y, int nrows)
{
    constexpr int NF = NCOL / 16;
    constexpr int NK = K / 32;

    const int t = threadIdx.x;
    const int lane = t & 63;
    const int w = t >> 6;
    const int row0 = blockIdx.x * 64 + w * 16;

    const int arow = row0 + (lane & 15);
    const bool rowok = arow < nrows;
    const float* xrow = X + (size_t)arow * K + ((lane >> 4) * 8);

    f32x4 acc[NF];
#pragma unroll
    for (int c = 0; c < NF; ++c) acc[c] = (f32x4){0.f, 0.f, 0.f, 0.f};

#pragma unroll 2
    for (int kk = 0; kk < NK; ++kk) {
        float4 v0 = make_float4(0.f, 0.f, 0.f, 0.f);
        float4 v1 = v0;
        if (rowok) {
            v0 = *(const float4*)&xrow[kk * 32];
            v1 = *(const float4*)&xrow[kk * 32 + 4];
        }
        if (ELU_IN) {
            v0.x = (v0.x > 0.f) ? v0.x : expm1f(v0.x);
            v0.y = (v0.y > 0.f) ? v0.y : expm1f(v0.y);
            v0.z = (v0.z > 0.f) ? v0.z : expm1f(v0.z);
            v0.w = (v0.w > 0.f) ? v0.w : expm1f(v0.w);
            v1.x = (v1.x > 0.f) ? v1.x : expm1f(v1.x);
            v1.y = (v1.y > 0.f) ? v1.y : expm1f(v1.y);
            v1.z = (v1.z > 0.f) ? v1.z : expm1f(v1.z);
            v1.w = (v1.w > 0.f) ? v1.w : expm1f(v1.w);
        }
        float a[8] = {v0.x, v0.y, v0.z, v0.w, v1.x, v1.y, v1.z, v1.w};
        short8v ah, al;
#pragma unroll
        for (int j = 0; j < 8; ++j) {
            unsigned short hb = f2bf_rne(a[j]);
            ah[j] = (short)hb;
            al[j] = (short)f2bf_rne(a[j] - bf2f(hb));
        }
        const unsigned short* wfk = wf + (size_t)(kk * NF * 2) * 512 + lane * 8;
        short8v bh[NF], bl[NF];
#pragma unroll
        for (int c = 0; c < NF; ++c) {
            bh[c] = *(const short8v*)(wfk + (c * 2 + 0) * 512);
            bl[c] = *(const short8v*)(wfk + (c * 2 + 1) * 512);
        }
#pragma unroll
        for (int c = 0; c < NF; ++c) {
            acc[c] = __builtin_amdgcn_mfma_f32_16x16x32_bf16(ah, bh[c], acc[c], 0, 0, 0);
            acc[c] = __builtin_amdgcn_mfma_f32_16x16x32_bf16(al, bh[c], acc[c], 0, 0, 0);
            acc[c] = __builtin_amdgcn_mfma_f32_16x16x32_bf16(ah, bl[c], acc[c], 0, 0, 0);
        }
    }

#pragma unroll
    for (int c = 0; c < NF; ++c) {
        int gcol = c * 16 + (lane & 15);
        float bv = BIAS ? bias[gcol] : 0.f;
#pragma unroll
        for (int q = 0; q < 4; ++q) {
            int grow = row0 + (lane >> 4) * 4 + q;
            if (grow < nrows) {
                float o = acc[c][q] + bv;
                if (LRELU) o = (o > 0.f) ? o : 0.01f * o;
                Y[(size_t)grow * NCOL + gcol] = o;
            }
        }
    }
}

// ---------------------------------------------------------------------------
// Fused heads: Z[:, 0:64] = lrelu( lrelu(A@H1+b1) @ H2 + b2 )
// Stage 1: per-wave 16 rows x 128 cols MFMA (NF=8).
// Hand-off: C/D-layout accs -> bf16 hi/lo in regs -> per-wave LDS [16][136].
// Stage 2: A-frags from LDS, B-frags (NF=4) from fragment-ordered h2f.
// No inter-wave sync (each wave consumes only its own tile).
// ---------------------------------------------------------------------------
__global__ __launch_bounds__(256) void fused_heads_kernel(
    const float* __restrict__ X, const unsigned short* __restrict__ h1f,
    const unsigned short* __restrict__ h2f, const float* __restrict__ bcat1,
    const float* __restrict__ bcat2, float* __restrict__ Z, int nrows)
{
    constexpr int LDT = 136;  // 16-row stride pad: bank advance 4/row, 2-way (free)
    __shared__ unsigned short t1h[4][16][LDT];
    __shared__ unsigned short t1l[4][16][LDT];

    const int t = threadIdx.x;
    const int lane = t & 63;
    const int w = t >> 6;
    const int row0 = blockIdx.x * 64 + w * 16;

    const int arow = row0 + (lane & 15);
    const bool rowok = arow < nrows;
    const float* xrow = X + (size_t)arow * 128 + ((lane >> 4) * 8);

    // ---- stage 1: T1 = lrelu(A@H1 + b1), NF=8, NK=4 ----
    f32x4 acc[8];
#pragma unroll
    for (int c = 0; c < 8; ++c) acc[c] = (f32x4){0.f, 0.f, 0.f, 0.f};

#pragma unroll 2
    for (int kk = 0; kk < 4; ++kk) {
        float4 v0 = make_float4(0.f, 0.f, 0.f, 0.f);
        float4 v1 = v0;
        if (rowok) {
            v0 = *(const float4*)&xrow[kk * 32];
            v1 = *(const float4*)&xrow[kk * 32 + 4];
        }
        float a[8] = {v0.x, v0.y, v0.z, v0.w, v1.x, v1.y, v1.z, v1.w};
        short8v ah, al;
#pragma unroll
        for (int j = 0; j < 8; ++j) {
            unsigned short hb = f2bf_rne(a[j]);
            ah[j] = (short)hb;
            al[j] = (short)f2bf_rne(a[j] - bf2f(hb));
        }
        const unsigned short* wfk = h1f + (size_t)(kk * 16) * 512 + lane * 8;
        short8v bh[8], bl[8];
#pragma unroll
        for (int c = 0; c < 8; ++c) {
            bh[c] = *(const short8v*)(wfk + (c * 2 + 0) * 512);
            bl[c] = *(const short8v*)(wfk + (c * 2 + 1) * 512);
        }
#pragma unroll
        for (int c = 0; c < 8; ++c) {
            acc[c] = __builtin_amdgcn_mfma_f32_16x16x32_bf16(ah, bh[c], acc[c], 0, 0, 0);
            acc[c] = __builtin_amdgcn_mfma_f32_16x16x32_bf16(al, bh[c], acc[c], 0, 0, 0);
            acc[c] = __builtin_amdgcn_mfma_f32_16x16x32_bf16(ah, bl[c], acc[c], 0, 0, 0);
        }
    }

    // ---- hand-off: bias + lrelu + hi/lo split -> per-wave LDS ----
#pragma unroll
    for (int c = 0; c < 8; ++c) {
        int col = c * 16 + (lane & 15);
        float bv = bcat1[col];
#pragma unroll
        for (int q = 0; q < 4; ++q) {
            int r = (lane >> 4) * 4 + q;
            float o = acc[c][q] + bv;
            o = (o > 0.f) ? o : 0.01f * o;
            unsigned short hb = f2bf_rne(o);
            t1h[w][r][col] = hb;
            t1l[w][r][col] = f2bf_rne(o - bf2f(hb));
        }
    }

    // ---- stage 2: Z = lrelu(T1@H2 + b2), NF=4, NK=4 ----
    f32x4 acc2[4];
#pragma unroll
    for (int c = 0; c < 4; ++c) acc2[c] = (f32x4){0.f, 0.f, 0.f, 0.f};

#pragma unroll
    for (int kk = 0; kk < 4; ++kk) {
        int koff = kk * 32 + (lane >> 4) * 8;
        short8v ah = *(const short8v*)&t1h[w][lane & 15][koff];
        short8v al = *(const short8v*)&t1l[w][lane & 15][koff];
        const unsigned short* wfk = h2f + (size_t)(kk * 8) * 512 + lane * 8;
#pragma unroll
        for (int c = 0; c < 4; ++c) {
            short8v bh = *(const short8v*)(wfk + (c * 2 + 0) * 512);
            short8v bl = *(const short8v*)(wfk + (c * 2 + 1) * 512);
            acc2[c] = __builtin_amdgcn_mfma_f32_16x16x32_bf16(ah, bh, acc2[c], 0, 0, 0);
            acc2[c] = __builtin_amdgcn_mfma_f32_16x16x32_bf16(al, bh, acc2[c], 0, 0, 0);
            acc2[c] = __builtin_amdgcn_mfma_f32_16x16x32_bf16(ah, bl, acc2[c], 0, 0, 0);
        }
    }

#pragma unroll
    for (int c = 0; c < 4; ++c) {
        int gcol = c * 16 + (lane & 15);
        float bv = bcat2[gcol];
#pragma unroll
        for (int q = 0; q < 4; ++q) {
            int grow = row0 + (lane >> 4) * 4 + q;
            if (grow < nrows) {
                float o = acc2[c][q] + bv;
                o = (o > 0.f) ? o : 0.01f * o;
                Z[(size_t)grow * 64 + gcol] = o;
            }
        }
    }
}

// ---------------------------------------------------------------------------
// Gather (index-broadcast): out[d,:] = dis[d]*(h[d]*dis[d] + sum h[s]*dis[s])
// 32 lanes/node; up to 32 edge indices + dis loaded coalesced per round,
// shfl-broadcast; h-row loads independent (deep MLP).
// ---------------------------------------------------------------------------
__global__ __launch_bounds__(256) void gather_kernel(const float* __restrict__ h,
                                                     const int* __restrict__ row_ptr,
                                                     const int* __restrict__ csr,
                                                     const float* __restrict__ dis,
                                                     float* __restrict__ outp, int n) {
    int node = blockIdx.x * 8 + (threadIdx.x >> 5);
    int l = threadIdx.x & 31;
    if (node >= n) return;
    int beg = (node == 0) ? 0 : row_ptr[node - 1];
    int end = row_ptr[node];
    float dd = dis[node];
    const float4* h4 = (const float4*)h;
    float4 self = h4[(size_t)node * 32 + l];
    float ax = self.x * dd, ay = self.y * dd, az = self.z * dd, aw = self.w * dd;

    for (int j0 = beg; j0 < end; j0 += 32) {
        int cnt = end - j0; if (cnt > 32) cnt = 32;
        int idx = 0;
        if (j0 + l < end) idx = csr[j0 + l];
        float dsv = dis[idx];
        int k = 0;
        for (; k + 4 <= cnt; k += 4) {
            int s0 = __shfl(idx, k + 0, 32), s1 = __shfl(idx, k + 1, 32);
            int s2 = __shfl(idx, k + 2, 32), s3 = __shfl(idx, k + 3, 32);
            float d0 = __shfl(dsv, k + 0, 32), d1 = __shfl(dsv, k + 1, 32);
            float d2 = __shfl(dsv, k + 2, 32), d3 = __shfl(dsv, k + 3, 32);
            float4 v0 = h4[(size_t)s0 * 32 + l];
            float4 v1 = h4[(size_t)s1 * 32 + l];
            float4 v2 = h4[(size_t)s2 * 32 + l];
            float4 v3 = h4[(size_t)s3 * 32 + l];
            ax += v0.x * d0 + v1.x * d1 + v2.x * d2 + v3.x * d3;
            ay += v0.y * d0 + v1.y * d1 + v2.y * d2 + v3.y * d3;
            az += v0.z * d0 + v1.z * d1 + v2.z * d2 + v3.z * d3;
            aw += v0.w * d0 + v1.w * d1 + v2.w * d2 + v3.w * d3;
        }
        for (; k < cnt; ++k) {
            int s = __shfl(idx, k, 32);
            float ds = __shfl(dsv, k, 32);
            float4 v = h4[(size_t)s * 32 + l];
            ax += v.x * ds; ay += v.y * ds; az += v.z * ds; aw += v.w * ds;
        }
    }
    float4 o;
    o.x = ax * dd; o.y = ay * dd; o.z = az * dd; o.w = aw * dd;
    ((float4*)outp)[(size_t)node * 32 + l] = o;
}

// ---------------------------------------------------------------------------
// decoder (unchanged): Z layout [node][64] = [tf2(32) | tg2(32)]
// ---------------------------------------------------------------------------
__global__ void dot_kernel(const float* __restrict__ Z,
                           const int* __restrict__ ts, float* __restrict__ out, int m) {
    int gid = blockIdx.x * 256 + threadIdx.x;
    int s = gid >> 3;
    int l = gid & 7;
    if (s >= m) return;
    int ti = ts[2 * s + 0];
    int ui = ts[2 * s + 1];
    float4 a = *(const float4*)&Z[(size_t)ti * 64 + l * 4];
    float4 b = *(const float4*)&Z[(size_t)ui * 64 + 32 + l * 4];
    float d = a.x * b.x + a.y * b.y + a.z * b.z + a.w * b.w;
    d += __shfl_down(d, 4, 8);
    d += __shfl_down(d, 2, 8);
    d += __shfl_down(d, 1, 8);
    if (l == 0) out[s] = d;
}

// ---------------------------------------------------------------------------
extern "C" void kernel_launch(void* const* d_in, const int* in_sizes, int n_in,
                              void* d_out, int out_size, void* d_ws, size_t ws_size,
                              hipStream_t stream) {
    const float* x     = (const float*)d_in[0];
    const int*   ei    = (const int*)d_in[1];
    const int*   ts    = (const int*)d_in[2];
    const float* W1    = (const float*)d_in[3];
    const float* W2    = (const float*)d_in[4];
    const float* tf_w1 = (const float*)d_in[5];
    const float* tf_b1 = (const float*)d_in[6];
    const float* tf_w2 = (const float*)d_in[7];
    const float* tf_b2 = (const float*)d_in[8];
    const float* tg_w1 = (const float*)d_in[9];
    const float* tg_b1 = (const float*)d_in[10];
    const float* tg_w2 = (const float*)d_in[11];
    const float* tg_b2 = (const float*)d_in[12];
    float* out = (float*)d_out;

    const int n = in_sizes[0] / 256;   // 50000
    const int e = in_sizes[1] / 2;     // 640000
    const int m = in_sizes[2] / 2;     // 400000
    const int* src = ei;
    const int* dstp = ei + e;

    // workspace layout (float units):
    //   dis[50176] | row_ptr[50176] (partials at +50048) | ideg/csr[640064] |
    //   wfrag[73728] (147456 shorts) | bcat1[128] bcat2[64] | A | B | C
    float* wsf = (float*)d_ws;
    float* dis     = wsf;
    int*   row_ptr = (int*)(wsf + 50176);
    int*   partials = row_ptr + 50048;
    int*   ideg    = (int*)(wsf + 100352);
    int*   csr     = (int*)(wsf + 100352);
    unsigned short* wfrag = (unsigned short*)(wsf + 740416);
    unsigned short* w1f = wfrag;
    unsigned short* w2f = wfrag + 65536;
    unsigned short* h1f = wfrag + 98304;
    unsigned short* h2f = wfrag + 131072;
    float* bcat1 = wsf + 740416 + 73728;
    float* bcat2 = wsf + 814272;
    float* A = wsf + 814336;
    float* B = A + (size_t)n * 128;
    float* C = B + (size_t)n * 128;

    const int nb_n = (n + 255) / 256;
    const int nb_e = (e + 255) / 256;
    const int nsb  = (n + 1023) / 1024;  // 49
    const int gg   = (n + 7) / 8;
    const int gm   = (n + 63) / 64;      // 782

    // 1) CSR build + normalization (parallel scan)
    zero_ideg_kernel<<<nb_n, 256, 0, stream>>>(ideg, n);
    ideg_accum_kernel<<<nb_e, 256, 0, stream>>>(ideg, dstp, e);
    scan_blk_kernel<<<nsb, 256, 0, stream>>>(ideg, row_ptr, dis, partials, n);
    scan_part_kernel<<<1, 64, 0, stream>>>(partials, nsb);
    scan_add_kernel<<<nb_n, 256, 0, stream>>>(row_ptr, partials, n);
    fill_kernel<<<nb_e, 256, 0, stream>>>(src, dstp, row_ptr, csr, e);

    // 1b) weight prep (fragment order) + biases
    prep_weights_kernel<<<(147648 + 255) / 256, 256, 0, stream>>>(
        W1, W2, tf_w1, tf_b1, tf_w2, tf_b2, tg_w1, tg_b1, tg_w2, tg_b2,
        wfrag, bcat1, bcat2);

    // 2) layer 1: A = x@W1 ; B = gather(A)
    mfma_gemm_kernel<256, 128, false, false, false><<<gm, 256, 0, stream>>>(x, w1f, nullptr, A, n);
    gather_kernel<<<gg, 256, 0, stream>>>(A, row_ptr, csr, dis, B, n);

    // 3) layer 2: C = elu(B)@W2 ; A = gather(C)  (A = embed)
    mfma_gemm_kernel<128, 128, true, false, false><<<gm, 256, 0, stream>>>(B, w2f, nullptr, C, n);
    gather_kernel<<<gg, 256, 0, stream>>>(C, row_ptr, csr, dis, A, n);

    // 4) fused heads: C = lrelu(lrelu(A@H1+b1)@H2+b2), layout [node][tf2|tg2]
    fused_heads_kernel<<<gm, 256, 0, stream>>>(A, h1f, h2f, bcat1, bcat2, C, n);

    // 5) decoder
    dot_kernel<<<(m * 8 + 255) / 256, 256, 0, stream>>>(C, ts, out, m);
}

// Round 11
// 304.366 us; speedup vs baseline: 7.2487x; 1.1645x over previous
//
#include <hip/hip_runtime.h>
#include <hip/hip_bf16.h>
#include <math.h>

// Problem constants: N=50000, E=640000, M=400000
// D_IN=256, H1=128, H2=128, H3=64, D_OUT=32
//
// Round 11: identical resubmit of round 10 (container infra failure, no data).
// Round 10: fp16 storage for all randomly-read arrays (halve gather/dot
// L2-miss bytes): layer-GEMM outputs A,C -> _Float16 (gather input),
// fused-heads output Z -> _Float16 (dot input). Accumulation and the
// compensated-bf16 GEMM chain stay fp32. Gather reverted to round-8
// direct-index loop (round-9 shfl version regressed).

typedef __attribute__((ext_vector_type(8))) short short8v;     // 8 bf16 (4 VGPR)
typedef __attribute__((ext_vector_type(4))) float f32x4;       // MFMA acc
typedef __attribute__((ext_vector_type(4))) _Float16 half4v;   // 8B fp16 vector

__device__ inline unsigned short f2bf_rne(float f) {
    unsigned u = __float_as_uint(f);
    unsigned r = u + 0x7FFFu + ((u >> 16) & 1u);
    return (unsigned short)(r >> 16);
}
__device__ inline float bf2f(unsigned short h) {
    return __uint_as_float(((unsigned)h) << 16);
}

// ---------------------------------------------------------------------------
// CSR build + norm
// ---------------------------------------------------------------------------
__global__ void zero_ideg_kernel(int* __restrict__ ideg, int n) {
    int i = blockIdx.x * 256 + threadIdx.x;
    if (i < n) ideg[i] = 0;
}

__global__ void ideg_accum_kernel(int* __restrict__ ideg, const int* __restrict__ dst, int e) {
    int i = blockIdx.x * 256 + threadIdx.x;
    if (i < e) atomicAdd(&ideg[dst[i]], 1);
}

__global__ __launch_bounds__(256) void scan_blk_kernel(const int* __restrict__ ideg,
                                                       int* __restrict__ row_ptr,
                                                       float* __restrict__ dis,
                                                       int* __restrict__ partials, int n) {
    __shared__ int wsum[4];
    const int t = threadIdx.x;
    const int lane = t & 63;
    const int wid = t >> 6;
    const int i0 = blockIdx.x * 1024 + t * 4;
    int4 v = make_int4(0, 0, 0, 0);
    if (i0 + 3 < n) {
        v = *(const int4*)&ideg[i0];
    } else if (i0 < n) {
        v.x = ideg[i0];
        if (i0 + 1 < n) v.y = ideg[i0 + 1];
        if (i0 + 2 < n) v.z = ideg[i0 + 2];
    }
    if (i0 < n) {
        dis[i0] = rsqrtf(1.f + (float)v.x);
        if (i0 + 1 < n) dis[i0 + 1] = rsqrtf(1.f + (float)v.y);
        if (i0 + 2 < n) dis[i0 + 2] = rsqrtf(1.f + (float)v.z);
        if (i0 + 3 < n) dis[i0 + 3] = rsqrtf(1.f + (float)v.w);
    }
    int s = v.x + v.y + v.z + v.w;
    int incl = s;
#pragma unroll
    for (int off = 1; off < 64; off <<= 1) {
        int tv = __shfl_up(incl, off, 64);
        if (lane >= off) incl += tv;
    }
    if (lane == 63) wsum[wid] = incl;
    __syncthreads();
    if (t == 0) {
        int a = 0;
#pragma unroll
        for (int ww = 0; ww < 4; ++ww) { int tmp = wsum[ww]; wsum[ww] = a; a += tmp; }
    }
    __syncthreads();
    int ex = wsum[wid] + incl - s;
    if (i0 < n) {
        row_ptr[i0] = ex;
        if (i0 + 1 < n) row_ptr[i0 + 1] = ex + v.x;
        if (i0 + 2 < n) row_ptr[i0 + 2] = ex + v.x + v.y;
        if (i0 + 3 < n) row_ptr[i0 + 3] = ex + v.x + v.y + v.z;
    }
    if (t == 255) partials[blockIdx.x] = wsum[3] + incl;
}

__global__ void scan_part_kernel(int* __restrict__ partials, int nb) {
    int lane = threadIdx.x;
    int v = (lane < nb) ? partials[lane] : 0;
    int incl = v;
#pragma unroll
    for (int off = 1; off < 64; off <<= 1) {
        int tv = __shfl_up(incl, off, 64);
        if (lane >= off) incl += tv;
    }
    if (lane < nb) partials[lane] = incl - v;
}

__global__ void scan_add_kernel(int* __restrict__ row_ptr, const int* __restrict__ partials, int n) {
    int i = blockIdx.x * 256 + threadIdx.x;
    if (i < n) row_ptr[i] += partials[i >> 10];
}

__global__ void fill_kernel(const int* __restrict__ src, const int* __restrict__ dst,
                            int* __restrict__ row_ptr, int* __restrict__ csr, int e) {
    int i = blockIdx.x * 256 + threadIdx.x;
    if (i < e) {
        int d = dst[i];
        int pos = atomicAdd(&row_ptr[d], 1);
        csr[pos] = src[i];
    }
}

// ---------------------------------------------------------------------------
// Weight prep in MFMA-fragment order.
// ---------------------------------------------------------------------------
__global__ void prep_weights_kernel(
    const float* __restrict__ W1, const float* __restrict__ W2,
    const float* __restrict__ tfw1, const float* __restrict__ tfb1,
    const float* __restrict__ tfw2, const float* __restrict__ tfb2,
    const float* __restrict__ tgw1, const float* __restrict__ tgb1,
    const float* __restrict__ tgw2, const float* __restrict__ tgb2,
    unsigned short* __restrict__ wf,
    float* __restrict__ bcat1, float* __restrict__ bcat2)
{
    int id = blockIdx.x * 256 + threadIdx.x;
    if (id >= 147456) {
        if (id < 147456 + 128) {
            int c = id - 147456;
            bcat1[c] = (c < 64) ? tfb1[c] : tgb1[c - 64];
        } else if (id < 147456 + 192) {
            int c = id - 147456 - 128;
            bcat2[c] = (c < 32) ? tfb2[c] : tgb2[c - 32];
        }
        return;
    }
    int base, NF;
    int lid;
    if (id < 65536)       { base = 0;      NF = 8; lid = id; }
    else if (id < 98304)  { base = 65536;  NF = 8; lid = id - 65536; }
    else if (id < 131072) { base = 98304;  NF = 8; lid = id - 98304; }
    else                  { base = 131072; NF = 4; lid = id - 131072; }

    int j    = lid & 7;
    int lane = (lid >> 3) & 63;
    int h    = (lid >> 9) & 1;
    int rest = lid >> 10;
    int c    = rest % NF;
    int kk   = rest / NF;
    int k    = kk * 32 + (lane >> 4) * 8 + j;
    int col  = c * 16 + (lane & 15);

    float w;
    if (id < 65536) {                 // W1: [256][128]
        w = W1[k * 128 + col];
    } else if (id < 98304) {          // W2: [128][128]
        w = W2[k * 128 + col];
    } else if (id < 131072) {         // H1 cat: [128][128] = [tf_w1 | tg_w1]
        w = (col < 64) ? tfw1[k * 64 + col] : tgw1[k * 64 + (col - 64)];
    } else {                          // H2 block-diag: [128][64]
        w = 0.f;
        if (k < 64 && col < 32) w = tfw2[k * 32 + col];
        else if (k >= 64 && col >= 32) w = tgw2[(k - 64) * 32 + (col - 32)];
    }
    unsigned short hb = f2bf_rne(w);
    wf[base + lid] = h ? f2bf_rne(w - bf2f(hb)) : hb;
}

// ---------------------------------------------------------------------------
// LDS-free MFMA GEMM. OUT_HALF: write _Float16 (for gather-consumed outputs).
// ---------------------------------------------------------------------------
template <int K, int NCOL, bool ELU_IN, bool LRELU, bool BIAS, bool OUT_HALF>
__global__ __launch_bounds__(256) void mfma_gemm_kernel(
    const float* __restrict__ X, const unsigned short* __restrict__ wf,
    const float* __restrict__ bias, void* __restrict__ Yv, int nrows)
{
    constexpr int NF = NCOL / 16;
    constexpr int NK = K / 32;

    const int t = threadIdx.x;
    const int lane = t & 63;
    const int w = t >> 6;
    const int row0 = blockIdx.x * 64 + w * 16;

    const int arow = row0 + (lane & 15);
    const bool rowok = arow < nrows;
    const float* xrow = X + (size_t)arow * K + ((lane >> 4) * 8);

    f32x4 acc[NF];
#pragma unroll
    for (int c = 0; c < NF; ++c) acc[c] = (f32x4){0.f, 0.f, 0.f, 0.f};

#pragma unroll 2
    for (int kk = 0; kk < NK; ++kk) {
        float4 v0 = make_float4(0.f, 0.f, 0.f, 0.f);
        float4 v1 = v0;
        if (rowok) {
            v0 = *(const float4*)&xrow[kk * 32];
            v1 = *(const float4*)&xrow[kk * 32 + 4];
        }
        if (ELU_IN) {
            v0.x = (v0.x > 0.f) ? v0.x : expm1f(v0.x);
            v0.y = (v0.y > 0.f) ? v0.y : expm1f(v0.y);
            v0.z = (v0.z > 0.f) ? v0.z : expm1f(v0.z);
            v0.w = (v0.w > 0.f) ? v0.w : expm1f(v0.w);
            v1.x = (v1.x > 0.f) ? v1.x : expm1f(v1.x);
            v1.y = (v1.y > 0.f) ? v1.y : expm1f(v1.y);
            v1.z = (v1.z > 0.f) ? v1.z : expm1f(v1.z);
            v1.w = (v1.w > 0.f) ? v1.w : expm1f(v1.w);
        }
        float a[8] = {v0.x, v0.y, v0.z, v0.w, v1.x, v1.y, v1.z, v1.w};
        short8v ah, al;
#pragma unroll
        for (int j = 0; j < 8; ++j) {
            unsigned short hb = f2bf_rne(a[j]);
            ah[j] = (short)hb;
            al[j] = (short)f2bf_rne(a[j] - bf2f(hb));
        }
        const unsigned short* wfk = wf + (size_t)(kk * NF * 2) * 512 + lane * 8;
        short8v bh[NF], bl[NF];
#pragma unroll
        for (int c = 0; c < NF; ++c) {
            bh[c] = *(const short8v*)(wfk + (c * 2 + 0) * 512);
            bl[c] = *(const short8v*)(wfk + (c * 2 + 1) * 512);
        }
#pragma unroll
        for (int c = 0; c < NF; ++c) {
            acc[c] = __builtin_amdgcn_mfma_f32_16x16x32_bf16(ah, bh[c], acc[c], 0, 0, 0);
            acc[c] = __builtin_amdgcn_mfma_f32_16x16x32_bf16(al, bh[c], acc[c], 0, 0, 0);
            acc[c] = __builtin_amdgcn_mfma_f32_16x16x32_bf16(ah, bl[c], acc[c], 0, 0, 0);
        }
    }

#pragma unroll
    for (int c = 0; c < NF; ++c) {
        int gcol = c * 16 + (lane & 15);
        float bv = BIAS ? bias[gcol] : 0.f;
#pragma unroll
        for (int q = 0; q < 4; ++q) {
            int grow = row0 + (lane >> 4) * 4 + q;
            if (grow < nrows) {
                float o = acc[c][q] + bv;
                if (LRELU) o = (o > 0.f) ? o : 0.01f * o;
                if (OUT_HALF) ((_Float16*)Yv)[(size_t)grow * NCOL + gcol] = (_Float16)o;
                else          ((float*)Yv)[(size_t)grow * NCOL + gcol] = o;
            }
        }
    }
}

// ---------------------------------------------------------------------------
// Fused heads: Z[:, 0:64] = lrelu( lrelu(A@H1+b1) @ H2 + b2 ), Z in fp16.
// ---------------------------------------------------------------------------
__global__ __launch_bounds__(256) void fused_heads_kernel(
    const float* __restrict__ X, const unsigned short* __restrict__ h1f,
    const unsigned short* __restrict__ h2f, const float* __restrict__ bcat1,
    const float* __restrict__ bcat2, _Float16* __restrict__ Z, int nrows)
{
    constexpr int LDT = 136;
    __shared__ unsigned short t1h[4][16][LDT];
    __shared__ unsigned short t1l[4][16][LDT];

    const int t = threadIdx.x;
    const int lane = t & 63;
    const int w = t >> 6;
    const int row0 = blockIdx.x * 64 + w * 16;

    const int arow = row0 + (lane & 15);
    const bool rowok = arow < nrows;
    const float* xrow = X + (size_t)arow * 128 + ((lane >> 4) * 8);

    f32x4 acc[8];
#pragma unroll
    for (int c = 0; c < 8; ++c) acc[c] = (f32x4){0.f, 0.f, 0.f, 0.f};

#pragma unroll 2
    for (int kk = 0; kk < 4; ++kk) {
        float4 v0 = make_float4(0.f, 0.f, 0.f, 0.f);
        float4 v1 = v0;
        if (rowok) {
            v0 = *(const float4*)&xrow[kk * 32];
            v1 = *(const float4*)&xrow[kk * 32 + 4];
        }
        float a[8] = {v0.x, v0.y, v0.z, v0.w, v1.x, v1.y, v1.z, v1.w};
        short8v ah, al;
#pragma unroll
        for (int j = 0; j < 8; ++j) {
            unsigned short hb = f2bf_rne(a[j]);
            ah[j] = (short)hb;
            al[j] = (short)f2bf_rne(a[j] - bf2f(hb));
        }
        const unsigned short* wfk = h1f + (size_t)(kk * 16) * 512 + lane * 8;
        short8v bh[8], bl[8];
#pragma unroll
        for (int c = 0; c < 8; ++c) {
            bh[c] = *(const short8v*)(wfk + (c * 2 + 0) * 512);
            bl[c] = *(const short8v*)(wfk + (c * 2 + 1) * 512);
        }
#pragma unroll
        for (int c = 0; c < 8; ++c) {
            acc[c] = __builtin_amdgcn_mfma_f32_16x16x32_bf16(ah, bh[c], acc[c], 0, 0, 0);
            acc[c] = __builtin_amdgcn_mfma_f32_16x16x32_bf16(al, bh[c], acc[c], 0, 0, 0);
            acc[c] = __builtin_amdgcn_mfma_f32_16x16x32_bf16(ah, bl[c], acc[c], 0, 0, 0);
        }
    }

#pragma unroll
    for (int c = 0; c < 8; ++c) {
        int col = c * 16 + (lane & 15);
        float bv = bcat1[col];
#pragma unroll
        for (int q = 0; q < 4; ++q) {
            int r = (lane >> 4) * 4 + q;
            float o = acc[c][q] + bv;
            o = (o > 0.f) ? o : 0.01f * o;
            unsigned short hb = f2bf_rne(o);
            t1h[w][r][col] = hb;
            t1l[w][r][col] = f2bf_rne(o - bf2f(hb));
        }
    }

    f32x4 acc2[4];
#pragma unroll
    for (int c = 0; c < 4; ++c) acc2[c] = (f32x4){0.f, 0.f, 0.f, 0.f};

#pragma unroll
    for (int kk = 0; kk < 4; ++kk) {
        int koff = kk * 32 + (lane >> 4) * 8;
        short8v ah = *(const short8v*)&t1h[w][lane & 15][koff];
        short8v al = *(const short8v*)&t1l[w][lane & 15][koff];
        const unsigned short* wfk = h2f + (size_t)(kk * 8) * 512 + lane * 8;
#pragma unroll
        for (int c = 0; c < 4; ++c) {
            short8v bh = *(const short8v*)(wfk + (c * 2 + 0) * 512);
            short8v bl = *(const short8v*)(wfk + (c * 2 + 1) * 512);
            acc2[c] = __builtin_amdgcn_mfma_f32_16x16x32_bf16(ah, bh, acc2[c], 0, 0, 0);
            acc2[c] = __builtin_amdgcn_mfma_f32_16x16x32_bf16(al, bh, acc2[c], 0, 0, 0);
            acc2[c] = __builtin_amdgcn_mfma_f32_16x16x32_bf16(ah, bl, acc2[c], 0, 0, 0);
        }
    }

#pragma unroll
    for (int c = 0; c < 4; ++c) {
        int gcol = c * 16 + (lane & 15);
        float bv = bcat2[gcol];
#pragma unroll
        for (int q = 0; q < 4; ++q) {
            int grow = row0 + (lane >> 4) * 4 + q;
            if (grow < nrows) {
                float o = acc2[c][q] + bv;
                o = (o > 0.f) ? o : 0.01f * o;
                Z[(size_t)grow * 64 + gcol] = (_Float16)o;
            }
        }
    }
}

// ---------------------------------------------------------------------------
// Gather (fp16 input, fp32 accumulate/output), direct-index loop.
// out[d,:] = dis[d]*(h[d]*dis[d] + sum h[s]*dis[s]); 32 lanes/node.
// ---------------------------------------------------------------------------
__global__ __launch_bounds__(256) void gather_kernel(const _Float16* __restrict__ h,
                                                     const int* __restrict__ row_ptr,
                                                     const int* __restrict__ csr,
                                                     const float* __restrict__ dis,
                                                     float* __restrict__ outp, int n) {
    int node = blockIdx.x * 8 + (threadIdx.x >> 5);
    int l = threadIdx.x & 31;
    if (node >= n) return;
    int beg = (node == 0) ? 0 : row_ptr[node - 1];
    int end = row_ptr[node];
    float dd = dis[node];
    const half4v* h4 = (const half4v*)h;
    half4v self = h4[(size_t)node * 32 + l];
    float ax = (float)self[0] * dd, ay = (float)self[1] * dd;
    float az = (float)self[2] * dd, aw = (float)self[3] * dd;
    int j = beg;
    for (; j + 4 <= end; j += 4) {
        int s0 = csr[j + 0], s1 = csr[j + 1], s2 = csr[j + 2], s3 = csr[j + 3];
        float d0 = dis[s0], d1 = dis[s1], d2 = dis[s2], d3 = dis[s3];
        half4v v0 = h4[(size_t)s0 * 32 + l];
        half4v v1 = h4[(size_t)s1 * 32 + l];
        half4v v2 = h4[(size_t)s2 * 32 + l];
        half4v v3 = h4[(size_t)s3 * 32 + l];
        ax += (float)v0[0] * d0 + (float)v1[0] * d1 + (float)v2[0] * d2 + (float)v3[0] * d3;
        ay += (float)v0[1] * d0 + (float)v1[1] * d1 + (float)v2[1] * d2 + (float)v3[1] * d3;
        az += (float)v0[2] * d0 + (float)v1[2] * d1 + (float)v2[2] * d2 + (float)v3[2] * d3;
        aw += (float)v0[3] * d0 + (float)v1[3] * d1 + (float)v2[3] * d2 + (float)v3[3] * d3;
    }
    for (; j < end; ++j) {
        int s = csr[j];
        float ds = dis[s];
        half4v v = h4[(size_t)s * 32 + l];
        ax += (float)v[0] * ds; ay += (float)v[1] * ds;
        az += (float)v[2] * ds; aw += (float)v[3] * ds;
    }
    float4 o;
    o.x = ax * dd; o.y = ay * dd; o.z = az * dd; o.w = aw * dd;
    ((float4*)outp)[(size_t)node * 32 + l] = o;
}

// ---------------------------------------------------------------------------
// decoder: Z fp16, layout [node][64] = [tf2(32) | tg2(32)]; 8 lanes/sample.
// ---------------------------------------------------------------------------
__global__ void dot_kernel(const _Float16* __restrict__ Z,
                           const int* __restrict__ ts, float* __restrict__ out, int m) {
    int gid = blockIdx.x * 256 + threadIdx.x;
    int s = gid >> 3;
    int l = gid & 7;
    if (s >= m) return;
    int ti = ts[2 * s + 0];
    int ui = ts[2 * s + 1];
    const half4v* Z4 = (const half4v*)Z;
    half4v a = Z4[(size_t)ti * 16 + l];
    half4v b = Z4[(size_t)ui * 16 + 8 + l];
    float d = (float)a[0] * (float)b[0] + (float)a[1] * (float)b[1]
            + (float)a[2] * (float)b[2] + (float)a[3] * (float)b[3];
    d += __shfl_down(d, 4, 8);
    d += __shfl_down(d, 2, 8);
    d += __shfl_down(d, 1, 8);
    if (l == 0) out[s] = d;
}

// ---------------------------------------------------------------------------
extern "C" void kernel_launch(void* const* d_in, const int* in_sizes, int n_in,
                              void* d_out, int out_size, void* d_ws, size_t ws_size,
                              hipStream_t stream) {
    const float* x     = (const float*)d_in[0];
    const int*   ei    = (const int*)d_in[1];
    const int*   ts    = (const int*)d_in[2];
    const float* W1    = (const float*)d_in[3];
    const float* W2    = (const float*)d_in[4];
    const float* tf_w1 = (const float*)d_in[5];
    const float* tf_b1 = (const float*)d_in[6];
    const float* tf_w2 = (const float*)d_in[7];
    const float* tf_b2 = (const float*)d_in[8];
    const float* tg_w1 = (const float*)d_in[9];
    const float* tg_b1 = (const float*)d_in[10];
    const float* tg_w2 = (const float*)d_in[11];
    const float* tg_b2 = (const float*)d_in[12];
    float* out = (float*)d_out;

    const int n = in_sizes[0] / 256;   // 50000
    const int e = in_sizes[1] / 2;     // 640000
    const int m = in_sizes[2] / 2;     // 400000
    const int* src = ei;
    const int* dstp = ei + e;

    // workspace layout (float units):
    //   dis[50176] | row_ptr[50176] (partials at +50048) | ideg/csr[640064] |
    //   wfrag[73728] (147456 shorts) | bcat1[128] bcat2[64] | A | B | C
    // A/C regions hold fp16 [n][128] during gather phases (fp32-sized alloc).
    float* wsf = (float*)d_ws;
    float* dis     = wsf;
    int*   row_ptr = (int*)(wsf + 50176);
    int*   partials = row_ptr + 50048;
    int*   ideg    = (int*)(wsf + 100352);
    int*   csr     = (int*)(wsf + 100352);
    unsigned short* wfrag = (unsigned short*)(wsf + 740416);
    unsigned short* w1f = wfrag;
    unsigned short* w2f = wfrag + 65536;
    unsigned short* h1f = wfrag + 98304;
    unsigned short* h2f = wfrag + 131072;
    float* bcat1 = wsf + 740416 + 73728;
    float* bcat2 = wsf + 814272;
    float* A = wsf + 814336;
    float* B = A + (size_t)n * 128;
    float* C = B + (size_t)n * 128;
    _Float16* A16 = (_Float16*)A;
    _Float16* C16 = (_Float16*)C;
    _Float16* Z16 = (_Float16*)C;   // heads output overlays C region

    const int nb_n = (n + 255) / 256;
    const int nb_e = (e + 255) / 256;
    const int nsb  = (n + 1023) / 1024;  // 49
    const int gg   = (n + 7) / 8;
    const int gm   = (n + 63) / 64;      // 782

    // 1) CSR build + normalization (parallel scan)
    zero_ideg_kernel<<<nb_n, 256, 0, stream>>>(ideg, n);
    ideg_accum_kernel<<<nb_e, 256, 0, stream>>>(ideg, dstp, e);
    scan_blk_kernel<<<nsb, 256, 0, stream>>>(ideg, row_ptr, dis, partials, n);
    scan_part_kernel<<<1, 64, 0, stream>>>(partials, nsb);
    scan_add_kernel<<<nb_n, 256, 0, stream>>>(row_ptr, partials, n);
    fill_kernel<<<nb_e, 256, 0, stream>>>(src, dstp, row_ptr, csr, e);

    // 1b) weight prep (fragment order) + biases
    prep_weights_kernel<<<(147648 + 255) / 256, 256, 0, stream>>>(
        W1, W2, tf_w1, tf_b1, tf_w2, tf_b2, tg_w1, tg_b1, tg_w2, tg_b2,
        wfrag, bcat1, bcat2);

    // 2) layer 1: A16 = x@W1 (fp16 out) ; B = gather(A16) (fp32)
    mfma_gemm_kernel<256, 128, false, false, false, true><<<gm, 256, 0, stream>>>(x, w1f, nullptr, A16, n);
    gather_kernel<<<gg, 256, 0, stream>>>(A16, row_ptr, csr, dis, B, n);

    // 3) layer 2: C16 = elu(B)@W2 (fp16 out) ; A = gather(C16) (fp32 embed)
    mfma_gemm_kernel<128, 128, true, false, false, true><<<gm, 256, 0, stream>>>(B, w2f, nullptr, C16, n);
    gather_kernel<<<gg, 256, 0, stream>>>(C16, row_ptr, csr, dis, A, n);

    // 4) fused heads: Z16 = lrelu(lrelu(A@H1+b1)@H2+b2), fp16 [node][tf2|tg2]
    fused_heads_kernel<<<gm, 256, 0, stream>>>(A, h1f, h2f, bcat1, bcat2, Z16, n);

    // 5) decoder
    dot_kernel<<<(m * 8 + 255) / 256, 256, 0, stream>>>(Z16, ts, out, m);
}